// Round 10
// baseline (274.271 us; speedup 1.0000x reference)
//
#include <hip/hip_runtime.h>
#include <hip/hip_bf16.h>
#include <stdint.h>

typedef __bf16 bf16x8 __attribute__((ext_vector_type(8)));
typedef float f32x4 __attribute__((ext_vector_type(4)));
typedef unsigned long long u64;

union BFrag { uint32_t u[4]; u64 q[2]; bf16x8 v; };

// truncation split: f = hi + lo (+ O(2^-17) on lo)
__device__ __forceinline__ void split1(float f, uint32_t& hi, uint32_t& lo) {
  uint32_t b = __float_as_uint(f);
  hi = b >> 16;
  float fl = f - __uint_as_float(b & 0xFFFF0000u);
  lo = __float_as_uint(fl) >> 16;
}

// ---------------------------------------------------------------------------
// K0: pack conv1 weights into MFMA B-fragments (hi/lo bf16).
// id = ((jf*4 + g)*16 + n)*8 + j ; n=(o,half), k-slot=(kx=2g+(j>>2), c=j&3),
// ky = jf - half. Invalid (c==3 | kx==7 | ky out of range) -> 0.
// ---------------------------------------------------------------------------
__global__ __launch_bounds__(256) void k0_wprep(
    const float* __restrict__ w1, unsigned short* __restrict__ wpHi,
    unsigned short* __restrict__ wpLo) {
  int id = blockIdx.x * 256 + threadIdx.x;
  if (id >= 4096) return;
  int j = id & 7, n = (id >> 3) & 15, g = (id >> 7) & 3, jf = id >> 9;
  int o = n & 7, half = n >> 3;
  int ky = jf - half, c = j & 3, kx = 2 * g + (j >> 2);
  float f = 0.f;
  if (c < 3 && kx < 7 && ky >= 0 && ky < 7)
    f = w1[o * 147 + c * 49 + ky * 7 + kx];
  uint32_t h, l;
  split1(f, h, l);
  wpHi[id] = (unsigned short)h;
  wpLo[id] = (unsigned short)l;
}

// ---------------------------------------------------------------------------
// K1 v3: conv1 + maxpool2 + relu via MFMA 16x16x32 bf16, jf-OUTER schedule.
// Only one B-pair (8 VGPR) live at a time (prefetch next while computing)
// vs v2's 64-reg B residency -> ~5 waves/SIMD instead of 3.
// A-rows re-read from LDS per jf (conflict-free, LDS had headroom).
// ---------------------------------------------------------------------------
__global__ __launch_bounds__(256) void k1_mfma(
    const float* __restrict__ x, const unsigned short* __restrict__ wpHi,
    const unsigned short* __restrict__ wpLo, const float* __restrict__ bias,
    float* __restrict__ out) {
  __shared__ unsigned short sH[2 * 70 * 24 * 4];  // [plane][row 70][col 24][c 4]
  const int b = blockIdx.z;
  const int x0 = blockIdx.x * 16;
  const int y0blk = blockIdx.y * 64;
  const int tid = threadIdx.x;
  const int lane = tid & 63, wid = tid >> 6;
  const int n = lane & 15, g = lane >> 4;

  // ---- stage input tile: rows y0blk..+69, cols x0..+23, split f32->hi/lo
  const float* xb = x + (size_t)b * 3 * 50176;
  for (int pos = tid; pos < 70 * 24; pos += 256) {
    int row = pos / 24, col = pos % 24;
    int gy = y0blk + row; gy = gy < 223 ? gy : 223;
    int gx = x0 + col;    gx = gx < 223 ? gx : 223;
    const float* p = xb + (size_t)gy * 224 + gx;
    uint32_t h0, l0, h1, l1, h2, l2;
    split1(p[0], h0, l0);
    split1(p[50176], h1, l1);
    split1(p[100352], h2, l2);
    u64 hq = (u64)(h0 | (h1 << 16)) | ((u64)h2 << 32);
    u64 lq = (u64)(l0 | (l1 << 16)) | ((u64)l2 << 32);
    *(u64*)&sH[pos * 4] = hq;           // hi plane
    *(u64*)&sH[6720 + pos * 4] = lq;    // lo plane
  }
  __syncthreads();

  const int y0w = y0blk + wid * 16;
  if (y0w <= 217) {
    f32x4 acc[8];
#pragma unroll
    for (int i = 0; i < 8; ++i) acc[i] = (f32x4){0.f, 0.f, 0.f, 0.f};

    const int mg = n + 2 * g;  // LDS col = conv-x offset (lane&15) + 2g
    const int rbase = wid * 16;
    const int bidx = (g * 16 + n) * 8;  // lane's B-frag base (jf stride 512)

    BFrag curH, curL, nxtH, nxtL;
    {
      uint4 th = *(const uint4*)&wpHi[bidx];
      uint4 tl = *(const uint4*)&wpLo[bidx];
      curH.u[0] = th.x; curH.u[1] = th.y; curH.u[2] = th.z; curH.u[3] = th.w;
      curL.u[0] = tl.x; curL.u[1] = tl.y; curL.u[2] = tl.z; curL.u[3] = tl.w;
    }
#pragma unroll
    for (int jf = 0; jf < 8; ++jf) {
      if (jf < 7) {
        uint4 th = *(const uint4*)&wpHi[bidx + (jf + 1) * 512];
        uint4 tl = *(const uint4*)&wpLo[bidx + (jf + 1) * 512];
        nxtH.u[0] = th.x; nxtH.u[1] = th.y; nxtH.u[2] = th.z; nxtH.u[3] = th.w;
        nxtL.u[0] = tl.x; nxtL.u[1] = tl.y; nxtL.u[2] = tl.z; nxtL.u[3] = tl.w;
      }
#pragma unroll
      for (int i = 0; i < 8; ++i) {
        const int t = 2 * i + jf;
        const int s0 = ((rbase + t) * 24 + mg) * 4;
        BFrag ah, al;
        ah.q[0] = *(const u64*)&sH[s0];
        ah.q[1] = *(const u64*)&sH[s0 + 4];
        al.q[0] = *(const u64*)&sH[6720 + s0];
        al.q[1] = *(const u64*)&sH[6720 + s0 + 4];
        acc[i] = __builtin_amdgcn_mfma_f32_16x16x32_bf16(ah.v, curH.v, acc[i], 0, 0, 0);
        acc[i] = __builtin_amdgcn_mfma_f32_16x16x32_bf16(ah.v, curL.v, acc[i], 0, 0, 0);
        acc[i] = __builtin_amdgcn_mfma_f32_16x16x32_bf16(al.v, curH.v, acc[i], 0, 0, 0);
      }
      curH = nxtH; curL = nxtL;  // renamed away by full unroll
    }

    // ---- epilogue: pool-x in-lane (reg pairs), pool-y via shfl_xor(8)
    const int o = n & 7;
    const float bs = bias[o];
    const int px0 = x0 / 2 + 2 * g;
    const int py0 = y0w / 2;
#pragma unroll
    for (int i = 0; i < 8; ++i) {
      float v0 = fmaxf(acc[i][0], acc[i][1]);
      float v1 = fmaxf(acc[i][2], acc[i][3]);
      float p0 = __shfl_xor(v0, 8, 64);
      float p1 = __shfl_xor(v1, 8, 64);
      const int py = py0 + i;
      if (n < 8 && py < 109) {
        float m0 = fmaxf(v0, p0) + bs;
        float m1 = fmaxf(v1, p1) + bs;
        float* op = out + ((size_t)(b * 8 + o) * 109 + py) * 109 + px0;
        if (px0 < 109)     op[0] = fmaxf(m0, 0.f);
        if (px0 + 1 < 109) op[1] = fmaxf(m1, 0.f);
      }
    }
  }
}

__device__ __forceinline__ void loadrow6(float* r, const float* p) {
#pragma unroll
  for (int i = 0; i < 3; ++i) {
    float2 t = *(const float2*)(p + 2 * i);
    r[2 * i] = t.x; r[2 * i + 1] = t.y;
  }
}

// ---------------------------------------------------------------------------
// K2: conv2 (8->10, 5x5) + maxpool2 + relu. 13x13 pool tile, scalar weights.
// ---------------------------------------------------------------------------
__global__ __launch_bounds__(192) void k2_conv_pool(
    const float* __restrict__ in, const float* __restrict__ w,
    const float* __restrict__ bias, float* __restrict__ out) {
  __shared__ float s_in[8 * 30 * 30];
  const int b = blockIdx.z;
  const int PX0 = blockIdx.x * 13, PY0 = blockIdx.y * 13;
  const int X0 = PX0 * 2, Y0 = PY0 * 2;
  const int tid = threadIdx.x;

  for (int idx = tid; idx < 8 * 30 * 30; idx += 192) {
    int c = idx / 900, rem = idx % 900;
    int iy = rem / 30, ixx = rem % 30;
    s_in[idx] = in[((b * 8 + c) * 109 + Y0 + iy) * 109 + X0 + ixx];
  }
  __syncthreads();

  if (tid >= 169) return;
  const int py = tid / 13, px = tid % 13;
  float acc[10][4];
#pragma unroll
  for (int o = 0; o < 10; ++o)
    acc[o][0] = acc[o][1] = acc[o][2] = acc[o][3] = 0.f;

  for (int c = 0; c < 8; ++c) {
    const float* base = &s_in[c * 900 + 2 * px];
    const float* wc = w + c * 25;
    float rows[2][6];
    loadrow6(rows[0], base + (2 * py) * 30);
#pragma unroll
    for (int ky = 0; ky < 5; ++ky) {
      loadrow6(rows[(ky + 1) & 1], base + (2 * py + ky + 1) * 30);
      const float* r0 = rows[ky & 1];
      const float* r1 = rows[(ky + 1) & 1];
#pragma unroll
      for (int kx = 0; kx < 5; ++kx) {
        float i00 = r0[kx], i01 = r0[kx + 1];
        float i10 = r1[kx], i11 = r1[kx + 1];
#pragma unroll
        for (int o = 0; o < 10; ++o) {
          float wv = wc[o * 200 + ky * 5 + kx];
          acc[o][0] = fmaf(i00, wv, acc[o][0]);
          acc[o][1] = fmaf(i01, wv, acc[o][1]);
          acc[o][2] = fmaf(i10, wv, acc[o][2]);
          acc[o][3] = fmaf(i11, wv, acc[o][3]);
        }
      }
    }
  }

  int opy = PY0 + py, opx = PX0 + px;
#pragma unroll
  for (int o = 0; o < 10; ++o) {
    float m = fmaxf(fmaxf(acc[o][0], acc[o][1]), fmaxf(acc[o][2], acc[o][3]));
    m += bias[o];
    out[((b * 10 + o) * 52 + opy) * 52 + opx] = fmaxf(m, 0.f);
  }
}

// ---------------------------------------------------------------------------
// K3: fc1 split-K partial GEMM, 256 blocks x 2 chunks of 64.
// ---------------------------------------------------------------------------
__global__ __launch_bounds__(256) void k3_fc1_partial(
    const float* __restrict__ xs, const float* __restrict__ w,
    float* __restrict__ part) {
  __shared__ float sA[128 * 64];
  __shared__ float sW[64 * 33];
  const int p = blockIdx.x;
  const int tid = threadIdx.x;
  const int n = tid & 31, bg = tid >> 5;
  float acc[16];
#pragma unroll
  for (int i = 0; i < 16; ++i) acc[i] = 0.f;

  for (int ch = 0; ch < 2; ++ch) {
    const int k0 = p * 128 + ch * 64;
    __syncthreads();
    for (int idx = tid; idx < 8192; idx += 256) {
      int bb = idx >> 6, k = idx & 63;
      int gk = k0 + k;
      sA[idx] = (gk < 27040) ? xs[bb * 27040 + gk] : 0.f;
    }
    for (int idx = tid; idx < 2048; idx += 256) {
      int nn = idx >> 6, k = idx & 63;
      int gk = k0 + k;
      sW[k * 33 + nn] = (gk < 27040) ? w[nn * 27040 + gk] : 0.f;
    }
    __syncthreads();
    for (int k = 0; k < 64; k += 4) {
      float w0 = sW[(k + 0) * 33 + n];
      float w1 = sW[(k + 1) * 33 + n];
      float w2 = sW[(k + 2) * 33 + n];
      float w3 = sW[(k + 3) * 33 + n];
#pragma unroll
      for (int i = 0; i < 16; ++i) {
        float4 a = *(const float4*)&sA[(bg * 16 + i) * 64 + k];
        acc[i] = fmaf(a.x, w0, acc[i]);
        acc[i] = fmaf(a.y, w1, acc[i]);
        acc[i] = fmaf(a.z, w2, acc[i]);
        acc[i] = fmaf(a.w, w3, acc[i]);
      }
    }
  }
#pragma unroll
  for (int i = 0; i < 16; ++i)
    part[p * 4096 + (bg * 16 + i) * 32 + n] = acc[i];
}

// ---------------------------------------------------------------------------
// K4: reduce 256 partials -> h = relu(C + b1). 512 blocks, shfl-reduce.
// ---------------------------------------------------------------------------
__global__ __launch_bounds__(256) void k4_reduce(
    const float* __restrict__ part, const float* __restrict__ b1,
    float* __restrict__ h) {
  const int lane = threadIdx.x & 31;
  const int eloc = threadIdx.x >> 5;
  const int e = blockIdx.x * 8 + eloc;
  float s = 0.f;
#pragma unroll
  for (int pc = 0; pc < 8; ++pc) s += part[(pc * 32 + lane) * 4096 + e];
#pragma unroll
  for (int off = 16; off > 0; off >>= 1) s += __shfl_down(s, off, 32);
  if (lane == 0) h[e] = fmaxf(s + b1[e & 31], 0.f);
}

// ---------------------------------------------------------------------------
// K5: theta (recomputed per block) + fused affine_grid + bilinear sample.
// ---------------------------------------------------------------------------
__global__ __launch_bounds__(256) void k5_sample(
    const float* __restrict__ x, const float* __restrict__ h,
    const float* __restrict__ w2, const float* __restrict__ b2,
    float* __restrict__ out) {
  __shared__ float th[6];
  const int b = blockIdx.z;
  if (threadIdx.x < 6) {
    int j = threadIdx.x;
    float s = b2[j];
    for (int m = 0; m < 32; ++m) s = fmaf(h[b * 32 + m], w2[j * 32 + m], s);
    th[j] = s;
  }
  __syncthreads();

  const int pix = blockIdx.x * 256 + threadIdx.x;
  const int hh = pix / 224, ww = pix % 224;
  const float step = 2.0f / 223.0f;
  float gx = ww * step - 1.0f, gy = hh * step - 1.0f;
  float tx = th[0] * gx + th[1] * gy + th[2];
  float ty = th[3] * gx + th[4] * gy + th[5];
  float ix = (tx + 1.0f) * 0.5f * 223.0f;
  float iy = (ty + 1.0f) * 0.5f * 223.0f;
  float x0 = floorf(ix), y0 = floorf(iy);
  float x1 = x0 + 1.f, y1 = y0 + 1.f;
  float wx1 = ix - x0, wx0 = x1 - ix;
  float wy1 = iy - y0, wy0 = y1 - iy;
  float w00 = wx0 * wy0, w01 = wx1 * wy0, w10 = wx0 * wy1, w11 = wx1 * wy1;
  bool vx0 = (x0 >= 0.f) && (x0 <= 223.f);
  bool vx1 = (x1 >= 0.f) && (x1 <= 223.f);
  bool vy0 = (y0 >= 0.f) && (y0 <= 223.f);
  bool vy1 = (y1 >= 0.f) && (y1 <= 223.f);
  w00 = (vx0 && vy0) ? w00 : 0.f;
  w01 = (vx1 && vy0) ? w01 : 0.f;
  w10 = (vx0 && vy1) ? w10 : 0.f;
  w11 = (vx1 && vy1) ? w11 : 0.f;
  int xi0 = (int)fminf(fmaxf(x0, 0.f), 223.f);
  int xi1 = (int)fminf(fmaxf(x1, 0.f), 223.f);
  int yi0 = (int)fminf(fmaxf(y0, 0.f), 223.f);
  int yi1 = (int)fminf(fmaxf(y1, 0.f), 223.f);
#pragma unroll
  for (int c = 0; c < 3; ++c) {
    const float* img = x + (size_t)((b * 3 + c) * 224) * 224;
    float v = img[yi0 * 224 + xi0] * w00 + img[yi0 * 224 + xi1] * w01 +
              img[yi1 * 224 + xi0] * w10 + img[yi1 * 224 + xi1] * w11;
    out[((b * 3 + c) * 224 + hh) * 224 + ww] = v;
  }
}

extern "C" void kernel_launch(void* const* d_in, const int* in_sizes, int n_in,
                              void* d_out, int out_size, void* d_ws,
                              size_t ws_size, hipStream_t stream) {
  const float* x   = (const float*)d_in[0];
  const float* w1  = (const float*)d_in[1];
  const float* b1  = (const float*)d_in[2];
  const float* w2  = (const float*)d_in[3];
  const float* b2  = (const float*)d_in[4];
  const float* fw1 = (const float*)d_in[5];
  const float* fb1 = (const float*)d_in[6];
  const float* fw2 = (const float*)d_in[7];
  const float* fb2 = (const float*)d_in[8];
  float* out = (float*)d_out;

  float* ws   = (float*)d_ws;
  float* out1 = ws;                    // [128,8,109,109] = 12,166,144 f32
  float* xs   = out1 + 12166144;       // [128,10,52,52]  =  3,461,120 f32
  float* part = xs + 3461120;          // [256,128,32]    =  1,048,576 f32
  float* hbuf = part + 1048576;        // [128,32]        =      4,096 f32
  unsigned short* wpHi = (unsigned short*)(hbuf + 4096);  // 4096 us
  unsigned short* wpLo = wpHi + 4096;                     // 4096 us

  k0_wprep<<<16, 256, 0, stream>>>(w1, wpHi, wpLo);
  k1_mfma<<<dim3(14, 4, 128), 256, 0, stream>>>(x, wpHi, wpLo, b1, out1);
  k2_conv_pool<<<dim3(4, 4, 128), 192, 0, stream>>>(out1, w2, b2, xs);
  k3_fc1_partial<<<256, 256, 0, stream>>>(xs, fw1, part);
  k4_reduce<<<512, 256, 0, stream>>>(part, fb1, hbuf);
  k5_sample<<<dim3(196, 1, 128), 256, 0, stream>>>(x, hbuf, fw2, fb2, out);
}

// Round 11
// 241.727 us; speedup vs baseline: 1.1346x; 1.1346x over previous
//
#include <hip/hip_runtime.h>
#include <hip/hip_bf16.h>
#include <stdint.h>

typedef __bf16 bf16x8 __attribute__((ext_vector_type(8)));
typedef float f32x4 __attribute__((ext_vector_type(4)));
typedef unsigned long long u64;

union BFrag { uint32_t u[4]; u64 q[2]; bf16x8 v; };

// truncation split: f = hi + lo (+ O(2^-17) on lo)
__device__ __forceinline__ void split1(float f, uint32_t& hi, uint32_t& lo) {
  uint32_t b = __float_as_uint(f);
  hi = b >> 16;
  float fl = f - __uint_as_float(b & 0xFFFF0000u);
  lo = __float_as_uint(fl) >> 16;
}

// ---------------------------------------------------------------------------
// K0: pack conv1 weights into MFMA B-fragments (hi/lo bf16).
// id = ((jf*4 + g)*16 + n)*8 + j ; n=(o,half), k-slot=(kx=2g+(j>>2), c=j&3),
// ky = jf - half. Invalid (c==3 | kx==7 | ky out of range) -> 0.
// ---------------------------------------------------------------------------
__global__ __launch_bounds__(256) void k0_wprep(
    const float* __restrict__ w1, unsigned short* __restrict__ wpHi,
    unsigned short* __restrict__ wpLo) {
  int id = blockIdx.x * 256 + threadIdx.x;
  if (id >= 4096) return;
  int j = id & 7, n = (id >> 3) & 15, g = (id >> 7) & 3, jf = id >> 9;
  int o = n & 7, half = n >> 3;
  int ky = jf - half, c = j & 3, kx = 2 * g + (j >> 2);
  float f = 0.f;
  if (c < 3 && kx < 7 && ky >= 0 && ky < 7)
    f = w1[o * 147 + c * 49 + ky * 7 + kx];
  uint32_t h, l;
  split1(f, h, l);
  wpHi[id] = (unsigned short)h;
  wpLo[id] = (unsigned short)l;
}

// ---------------------------------------------------------------------------
// K1 (v2 core, R8-proven 128us): conv1 + maxpool2 + relu, MFMA 16x16x32 bf16.
// N = 8ch x 2ky pairing; B-frags resident; t-outer schedule.
// NEW: two-phase staging — 21 global loads issued into regs (MLP 21), then
// split+write LDS. Takes the ~6k-cycle serialized stage off the barrier path.
// ---------------------------------------------------------------------------
__global__ __launch_bounds__(256) void k1_mfma(
    const float* __restrict__ x, const unsigned short* __restrict__ wpHi,
    const unsigned short* __restrict__ wpLo, const float* __restrict__ bias,
    float* __restrict__ out) {
  __shared__ unsigned short sH[2 * 70 * 24 * 4];  // [plane][row 70][col 24][c 4]
  const int b = blockIdx.z;
  const int x0 = blockIdx.x * 16;
  const int y0blk = blockIdx.y * 64;
  const int tid = threadIdx.x;
  const int lane = tid & 63, wid = tid >> 6;
  const int n = lane & 15, g = lane >> 4;

  // ---- B fragments: 8 jf x (hi,lo), 16B aligned contiguous loads
  BFrag bhi[8], blo[8];
#pragma unroll
  for (int jf = 0; jf < 8; ++jf) {
    uint4 th = *(const uint4*)&wpHi[((jf * 4 + g) * 16 + n) * 8];
    uint4 tl = *(const uint4*)&wpLo[((jf * 4 + g) * 16 + n) * 8];
    bhi[jf].u[0] = th.x; bhi[jf].u[1] = th.y;
    bhi[jf].u[2] = th.z; bhi[jf].u[3] = th.w;
    blo[jf].u[0] = tl.x; blo[jf].u[1] = tl.y;
    blo[jf].u[2] = tl.z; blo[jf].u[3] = tl.w;
  }

  // ---- stage: phase 1 = issue all 21 loads into regs; phase 2 = split+write
  const float* xb = x + (size_t)b * 3 * 50176;
  float pv0[7], pv1[7], pv2[7];
#pragma unroll
  for (int u = 0; u < 7; ++u) {
    int pos = tid + u * 256;
    if (pos < 1680) {
      int row = pos / 24, col = pos % 24;
      int gy = y0blk + row; gy = gy < 223 ? gy : 223;
      int gx = x0 + col;    gx = gx < 223 ? gx : 223;
      const float* p = xb + (size_t)gy * 224 + gx;
      pv0[u] = p[0];
      pv1[u] = p[50176];
      pv2[u] = p[100352];
    }
  }
#pragma unroll
  for (int u = 0; u < 7; ++u) {
    int pos = tid + u * 256;
    if (pos < 1680) {
      uint32_t h0, l0, h1, l1, h2, l2;
      split1(pv0[u], h0, l0);
      split1(pv1[u], h1, l1);
      split1(pv2[u], h2, l2);
      u64 hq = (u64)(h0 | (h1 << 16)) | ((u64)h2 << 32);
      u64 lq = (u64)(l0 | (l1 << 16)) | ((u64)l2 << 32);
      *(u64*)&sH[pos * 4] = hq;           // hi plane
      *(u64*)&sH[6720 + pos * 4] = lq;    // lo plane
    }
  }
  __syncthreads();

  const int y0w = y0blk + wid * 16;
  if (y0w <= 217) {
    f32x4 acc[8];
#pragma unroll
    for (int i = 0; i < 8; ++i) acc[i] = (f32x4){0.f, 0.f, 0.f, 0.f};

    const int mg = n + 2 * g;  // LDS col = conv-x offset (lane&15) + 2g
    const int rbase = wid * 16;
#pragma unroll
    for (int t = 0; t < 22; ++t) {
      const int s0 = ((rbase + t) * 24 + mg) * 4;
      BFrag ah, al;
      ah.q[0] = *(const u64*)&sH[s0];
      ah.q[1] = *(const u64*)&sH[s0 + 4];
      al.q[0] = *(const u64*)&sH[6720 + s0];
      al.q[1] = *(const u64*)&sH[6720 + s0 + 4];
#pragma unroll
      for (int i = 0; i < 8; ++i) {
        const int jf = t - 2 * i;
        if (jf >= 0 && jf < 8) {
          acc[i] = __builtin_amdgcn_mfma_f32_16x16x32_bf16(ah.v, bhi[jf].v, acc[i], 0, 0, 0);
          acc[i] = __builtin_amdgcn_mfma_f32_16x16x32_bf16(ah.v, blo[jf].v, acc[i], 0, 0, 0);
          acc[i] = __builtin_amdgcn_mfma_f32_16x16x32_bf16(al.v, bhi[jf].v, acc[i], 0, 0, 0);
        }
      }
    }

    // ---- epilogue: pool-x in-lane (reg pairs), pool-y via shfl_xor(8)
    const int o = n & 7;
    const float bs = bias[o];
    const int px0 = x0 / 2 + 2 * g;
    const int py0 = y0w / 2;
#pragma unroll
    for (int i = 0; i < 8; ++i) {
      float v0 = fmaxf(acc[i][0], acc[i][1]);
      float v1 = fmaxf(acc[i][2], acc[i][3]);
      float p0 = __shfl_xor(v0, 8, 64);
      float p1 = __shfl_xor(v1, 8, 64);
      const int py = py0 + i;
      if (n < 8 && py < 109) {
        float m0 = fmaxf(v0, p0) + bs;
        float m1 = fmaxf(v1, p1) + bs;
        float* op = out + ((size_t)(b * 8 + o) * 109 + py) * 109 + px0;
        if (px0 < 109)     op[0] = fmaxf(m0, 0.f);
        if (px0 + 1 < 109) op[1] = fmaxf(m1, 0.f);
      }
    }
  }
}

__device__ __forceinline__ void loadrow6(float* r, const float* p) {
#pragma unroll
  for (int i = 0; i < 3; ++i) {
    float2 t = *(const float2*)(p + 2 * i);
    r[2 * i] = t.x; r[2 * i + 1] = t.y;
  }
}

// ---------------------------------------------------------------------------
// K2: conv2 (8->10, 5x5) + maxpool2 + relu. 13x13 pool tile, scalar weights.
// NEW: two-phase staging (groups of 8 -> MLP 8 instead of 1 per trip).
// ---------------------------------------------------------------------------
__global__ __launch_bounds__(192) void k2_conv_pool(
    const float* __restrict__ in, const float* __restrict__ w,
    const float* __restrict__ bias, float* __restrict__ out) {
  __shared__ float s_in[8 * 30 * 30];
  const int b = blockIdx.z;
  const int PX0 = blockIdx.x * 13, PY0 = blockIdx.y * 13;
  const int X0 = PX0 * 2, Y0 = PY0 * 2;
  const int tid = threadIdx.x;

#pragma unroll
  for (int bb = 0; bb < 5; ++bb) {
    float v[8];
#pragma unroll
    for (int u = 0; u < 8; ++u) {
      int idx = bb * 1536 + u * 192 + tid;
      if (idx < 7200) {
        int c = idx / 900, rem = idx % 900;
        int iy = rem / 30, ixx = rem % 30;
        v[u] = in[((b * 8 + c) * 109 + Y0 + iy) * 109 + X0 + ixx];
      }
    }
#pragma unroll
    for (int u = 0; u < 8; ++u) {
      int idx = bb * 1536 + u * 192 + tid;
      if (idx < 7200) s_in[idx] = v[u];
    }
  }
  __syncthreads();

  if (tid >= 169) return;
  const int py = tid / 13, px = tid % 13;
  float acc[10][4];
#pragma unroll
  for (int o = 0; o < 10; ++o)
    acc[o][0] = acc[o][1] = acc[o][2] = acc[o][3] = 0.f;

  for (int c = 0; c < 8; ++c) {
    const float* base = &s_in[c * 900 + 2 * px];
    const float* wc = w + c * 25;
    float rows[2][6];
    loadrow6(rows[0], base + (2 * py) * 30);
#pragma unroll
    for (int ky = 0; ky < 5; ++ky) {
      loadrow6(rows[(ky + 1) & 1], base + (2 * py + ky + 1) * 30);
      const float* r0 = rows[ky & 1];
      const float* r1 = rows[(ky + 1) & 1];
#pragma unroll
      for (int kx = 0; kx < 5; ++kx) {
        float i00 = r0[kx], i01 = r0[kx + 1];
        float i10 = r1[kx], i11 = r1[kx + 1];
#pragma unroll
        for (int o = 0; o < 10; ++o) {
          float wv = wc[o * 200 + ky * 5 + kx];
          acc[o][0] = fmaf(i00, wv, acc[o][0]);
          acc[o][1] = fmaf(i01, wv, acc[o][1]);
          acc[o][2] = fmaf(i10, wv, acc[o][2]);
          acc[o][3] = fmaf(i11, wv, acc[o][3]);
        }
      }
    }
  }

  int opy = PY0 + py, opx = PX0 + px;
#pragma unroll
  for (int o = 0; o < 10; ++o) {
    float m = fmaxf(fmaxf(acc[o][0], acc[o][1]), fmaxf(acc[o][2], acc[o][3]));
    m += bias[o];
    out[((b * 10 + o) * 52 + opy) * 52 + opx] = fmaxf(m, 0.f);
  }
}

// ---------------------------------------------------------------------------
// K3: fc1 split-K partial GEMM, 256 blocks x 2 chunks of 64.
// NEW: two-phase staging for sA (4x8 groups) and sW (1x8 group).
// ---------------------------------------------------------------------------
__global__ __launch_bounds__(256) void k3_fc1_partial(
    const float* __restrict__ xs, const float* __restrict__ w,
    float* __restrict__ part) {
  __shared__ float sA[128 * 64];
  __shared__ float sW[64 * 33];
  const int p = blockIdx.x;
  const int tid = threadIdx.x;
  const int n = tid & 31, bg = tid >> 5;
  float acc[16];
#pragma unroll
  for (int i = 0; i < 16; ++i) acc[i] = 0.f;

  for (int ch = 0; ch < 2; ++ch) {
    const int k0 = p * 128 + ch * 64;
    __syncthreads();
#pragma unroll
    for (int bb = 0; bb < 4; ++bb) {
      float v[8];
#pragma unroll
      for (int u = 0; u < 8; ++u) {
        int idx = bb * 2048 + u * 256 + tid;
        int bbv = idx >> 6, k = idx & 63;
        int gk = k0 + k;
        v[u] = (gk < 27040) ? xs[bbv * 27040 + gk] : 0.f;
      }
#pragma unroll
      for (int u = 0; u < 8; ++u) {
        int idx = bb * 2048 + u * 256 + tid;
        sA[idx] = v[u];
      }
    }
    {
      float v[8];
#pragma unroll
      for (int u = 0; u < 8; ++u) {
        int idx = u * 256 + tid;
        int nn = idx >> 6, k = idx & 63;
        int gk = k0 + k;
        v[u] = (gk < 27040) ? w[nn * 27040 + gk] : 0.f;
      }
#pragma unroll
      for (int u = 0; u < 8; ++u) {
        int idx = u * 256 + tid;
        int nn = idx >> 6, k = idx & 63;
        sW[k * 33 + nn] = v[u];
      }
    }
    __syncthreads();
    for (int k = 0; k < 64; k += 4) {
      float w0 = sW[(k + 0) * 33 + n];
      float w1 = sW[(k + 1) * 33 + n];
      float w2 = sW[(k + 2) * 33 + n];
      float w3 = sW[(k + 3) * 33 + n];
#pragma unroll
      for (int i = 0; i < 16; ++i) {
        float4 a = *(const float4*)&sA[(bg * 16 + i) * 64 + k];
        acc[i] = fmaf(a.x, w0, acc[i]);
        acc[i] = fmaf(a.y, w1, acc[i]);
        acc[i] = fmaf(a.z, w2, acc[i]);
        acc[i] = fmaf(a.w, w3, acc[i]);
      }
    }
  }
#pragma unroll
  for (int i = 0; i < 16; ++i)
    part[p * 4096 + (bg * 16 + i) * 32 + n] = acc[i];
}

// ---------------------------------------------------------------------------
// K4: reduce 256 partials -> h = relu(C + b1). 512 blocks, shfl-reduce.
// ---------------------------------------------------------------------------
__global__ __launch_bounds__(256) void k4_reduce(
    const float* __restrict__ part, const float* __restrict__ b1,
    float* __restrict__ h) {
  const int lane = threadIdx.x & 31;
  const int eloc = threadIdx.x >> 5;
  const int e = blockIdx.x * 8 + eloc;
  float s = 0.f;
#pragma unroll
  for (int pc = 0; pc < 8; ++pc) s += part[(pc * 32 + lane) * 4096 + e];
#pragma unroll
  for (int off = 16; off > 0; off >>= 1) s += __shfl_down(s, off, 32);
  if (lane == 0) h[e] = fmaxf(s + b1[e & 31], 0.f);
}

// ---------------------------------------------------------------------------
// K5: theta (recomputed per block) + fused affine_grid + bilinear sample.
// ---------------------------------------------------------------------------
__global__ __launch_bounds__(256) void k5_sample(
    const float* __restrict__ x, const float* __restrict__ h,
    const float* __restrict__ w2, const float* __restrict__ b2,
    float* __restrict__ out) {
  __shared__ float th[6];
  const int b = blockIdx.z;
  if (threadIdx.x < 6) {
    int j = threadIdx.x;
    float s = b2[j];
    for (int m = 0; m < 32; ++m) s = fmaf(h[b * 32 + m], w2[j * 32 + m], s);
    th[j] = s;
  }
  __syncthreads();

  const int pix = blockIdx.x * 256 + threadIdx.x;
  const int hh = pix / 224, ww = pix % 224;
  const float step = 2.0f / 223.0f;
  float gx = ww * step - 1.0f, gy = hh * step - 1.0f;
  float tx = th[0] * gx + th[1] * gy + th[2];
  float ty = th[3] * gx + th[4] * gy + th[5];
  float ix = (tx + 1.0f) * 0.5f * 223.0f;
  float iy = (ty + 1.0f) * 0.5f * 223.0f;
  float x0 = floorf(ix), y0 = floorf(iy);
  float x1 = x0 + 1.f, y1 = y0 + 1.f;
  float wx1 = ix - x0, wx0 = x1 - ix;
  float wy1 = iy - y0, wy0 = y1 - iy;
  float w00 = wx0 * wy0, w01 = wx1 * wy0, w10 = wx0 * wy1, w11 = wx1 * wy1;
  bool vx0 = (x0 >= 0.f) && (x0 <= 223.f);
  bool vx1 = (x1 >= 0.f) && (x1 <= 223.f);
  bool vy0 = (y0 >= 0.f) && (y0 <= 223.f);
  bool vy1 = (y1 >= 0.f) && (y1 <= 223.f);
  w00 = (vx0 && vy0) ? w00 : 0.f;
  w01 = (vx1 && vy0) ? w01 : 0.f;
  w10 = (vx0 && vy1) ? w10 : 0.f;
  w11 = (vx1 && vy1) ? w11 : 0.f;
  int xi0 = (int)fminf(fmaxf(x0, 0.f), 223.f);
  int xi1 = (int)fminf(fmaxf(x1, 0.f), 223.f);
  int yi0 = (int)fminf(fmaxf(y0, 0.f), 223.f);
  int yi1 = (int)fminf(fmaxf(y1, 0.f), 223.f);
#pragma unroll
  for (int c = 0; c < 3; ++c) {
    const float* img = x + (size_t)((b * 3 + c) * 224) * 224;
    float v = img[yi0 * 224 + xi0] * w00 + img[yi0 * 224 + xi1] * w01 +
              img[yi1 * 224 + xi0] * w10 + img[yi1 * 224 + xi1] * w11;
    out[((b * 3 + c) * 224 + hh) * 224 + ww] = v;
  }
}

extern "C" void kernel_launch(void* const* d_in, const int* in_sizes, int n_in,
                              void* d_out, int out_size, void* d_ws,
                              size_t ws_size, hipStream_t stream) {
  const float* x   = (const float*)d_in[0];
  const float* w1  = (const float*)d_in[1];
  const float* b1  = (const float*)d_in[2];
  const float* w2  = (const float*)d_in[3];
  const float* b2  = (const float*)d_in[4];
  const float* fw1 = (const float*)d_in[5];
  const float* fb1 = (const float*)d_in[6];
  const float* fw2 = (const float*)d_in[7];
  const float* fb2 = (const float*)d_in[8];
  float* out = (float*)d_out;

  float* ws   = (float*)d_ws;
  float* out1 = ws;                    // [128,8,109,109] = 12,166,144 f32
  float* xs   = out1 + 12166144;       // [128,10,52,52]  =  3,461,120 f32
  float* part = xs + 3461120;          // [256,128,32]    =  1,048,576 f32
  float* hbuf = part + 1048576;        // [128,32]        =      4,096 f32
  unsigned short* wpHi = (unsigned short*)(hbuf + 4096);  // 4096 us
  unsigned short* wpLo = wpHi + 4096;                     // 4096 us

  k0_wprep<<<16, 256, 0, stream>>>(w1, wpHi, wpLo);
  k1_mfma<<<dim3(14, 4, 128), 256, 0, stream>>>(x, wpHi, wpLo, b1, out1);
  k2_conv_pool<<<dim3(4, 4, 128), 192, 0, stream>>>(out1, w2, b2, xs);
  k3_fc1_partial<<<256, 256, 0, stream>>>(xs, fw1, part);
  k4_reduce<<<512, 256, 0, stream>>>(part, fb1, hbuf);
  k5_sample<<<dim3(196, 1, 128), 256, 0, stream>>>(x, hbuf, fw2, fb2, out);
}

// Round 12
// 226.415 us; speedup vs baseline: 1.2114x; 1.0676x over previous
//
#include <hip/hip_runtime.h>
#include <hip/hip_bf16.h>
#include <stdint.h>

typedef __bf16 bf16x8 __attribute__((ext_vector_type(8)));
typedef float f32x4 __attribute__((ext_vector_type(4)));
typedef unsigned long long u64;

union BFrag { uint32_t u[4]; u64 q[2]; bf16x8 v; };

// truncation split: f = hi + lo (+ O(2^-17) on lo)
__device__ __forceinline__ void split1(float f, uint32_t& hi, uint32_t& lo) {
  uint32_t b = __float_as_uint(f);
  hi = b >> 16;
  float fl = f - __uint_as_float(b & 0xFFFF0000u);
  lo = __float_as_uint(fl) >> 16;
}

// ---------------------------------------------------------------------------
// K0: pack conv1 weights into MFMA B-fragments (hi/lo bf16).
// id = ((jf*4 + g)*16 + n)*8 + j ; n=(o,half), k-slot=(kx=2g+(j>>2), c=j&3),
// ky = jf - half. Invalid -> 0.
// ---------------------------------------------------------------------------
__global__ __launch_bounds__(256) void k0_wprep(
    const float* __restrict__ w1, unsigned short* __restrict__ wpHi,
    unsigned short* __restrict__ wpLo) {
  int id = blockIdx.x * 256 + threadIdx.x;
  if (id >= 4096) return;
  int j = id & 7, n = (id >> 3) & 15, g = (id >> 7) & 3, jf = id >> 9;
  int o = n & 7, half = n >> 3;
  int ky = jf - half, c = j & 3, kx = 2 * g + (j >> 2);
  float f = 0.f;
  if (c < 3 && kx < 7 && ky >= 0 && ky < 7)
    f = w1[o * 147 + c * 49 + ky * 7 + kx];
  uint32_t h, l;
  split1(f, h, l);
  wpHi[id] = (unsigned short)h;
  wpLo[id] = (unsigned short)l;
}

// ---------------------------------------------------------------------------
// K0b: pack conv2 weights. id = ((hk*4+g)*16 + n)*8 + j, hk = ky*2+h.
// n = o (<10 valid); k-slot = (kx = 2g+(j>>2) [>4 -> 0], c = 4h+(j&3)).
// ---------------------------------------------------------------------------
__global__ __launch_bounds__(256) void k0b_wprep(
    const float* __restrict__ w2, unsigned short* __restrict__ wpHi,
    unsigned short* __restrict__ wpLo) {
  int id = blockIdx.x * 256 + threadIdx.x;
  if (id >= 5120) return;
  int j = id & 7, n = (id >> 3) & 15, g = (id >> 7) & 3;
  int hk = id >> 9;                 // ky*2 + h, 0..9
  int h = hk & 1, ky = hk >> 1;
  int c = 4 * h + (j & 3), kx = 2 * g + (j >> 2);
  float f = 0.f;
  if (n < 10 && kx < 5)
    f = w2[n * 200 + c * 25 + ky * 5 + kx];
  uint32_t hh, ll;
  split1(f, hh, ll);
  wpHi[id] = (unsigned short)hh;
  wpLo[id] = (unsigned short)ll;
}

// ---------------------------------------------------------------------------
// K1 (R10-proven, 103us): conv1 + maxpool2 + relu, MFMA 16x16x32 bf16.
// ---------------------------------------------------------------------------
__global__ __launch_bounds__(256) void k1_mfma(
    const float* __restrict__ x, const unsigned short* __restrict__ wpHi,
    const unsigned short* __restrict__ wpLo, const float* __restrict__ bias,
    float* __restrict__ out) {
  __shared__ unsigned short sH[2 * 70 * 24 * 4];
  const int b = blockIdx.z;
  const int x0 = blockIdx.x * 16;
  const int y0blk = blockIdx.y * 64;
  const int tid = threadIdx.x;
  const int lane = tid & 63, wid = tid >> 6;
  const int n = lane & 15, g = lane >> 4;

  BFrag bhi[8], blo[8];
#pragma unroll
  for (int jf = 0; jf < 8; ++jf) {
    uint4 th = *(const uint4*)&wpHi[((jf * 4 + g) * 16 + n) * 8];
    uint4 tl = *(const uint4*)&wpLo[((jf * 4 + g) * 16 + n) * 8];
    bhi[jf].u[0] = th.x; bhi[jf].u[1] = th.y;
    bhi[jf].u[2] = th.z; bhi[jf].u[3] = th.w;
    blo[jf].u[0] = tl.x; blo[jf].u[1] = tl.y;
    blo[jf].u[2] = tl.z; blo[jf].u[3] = tl.w;
  }

  const float* xb = x + (size_t)b * 3 * 50176;
  float pv0[7], pv1[7], pv2[7];
#pragma unroll
  for (int u = 0; u < 7; ++u) {
    int pos = tid + u * 256;
    if (pos < 1680) {
      int row = pos / 24, col = pos % 24;
      int gy = y0blk + row; gy = gy < 223 ? gy : 223;
      int gx = x0 + col;    gx = gx < 223 ? gx : 223;
      const float* p = xb + (size_t)gy * 224 + gx;
      pv0[u] = p[0];
      pv1[u] = p[50176];
      pv2[u] = p[100352];
    }
  }
#pragma unroll
  for (int u = 0; u < 7; ++u) {
    int pos = tid + u * 256;
    if (pos < 1680) {
      uint32_t h0, l0, h1, l1, h2, l2;
      split1(pv0[u], h0, l0);
      split1(pv1[u], h1, l1);
      split1(pv2[u], h2, l2);
      u64 hq = (u64)(h0 | (h1 << 16)) | ((u64)h2 << 32);
      u64 lq = (u64)(l0 | (l1 << 16)) | ((u64)l2 << 32);
      *(u64*)&sH[pos * 4] = hq;
      *(u64*)&sH[6720 + pos * 4] = lq;
    }
  }
  __syncthreads();

  const int y0w = y0blk + wid * 16;
  if (y0w <= 217) {
    f32x4 acc[8];
#pragma unroll
    for (int i = 0; i < 8; ++i) acc[i] = (f32x4){0.f, 0.f, 0.f, 0.f};

    const int mg = n + 2 * g;
    const int rbase = wid * 16;
#pragma unroll
    for (int t = 0; t < 22; ++t) {
      const int s0 = ((rbase + t) * 24 + mg) * 4;
      BFrag ah, al;
      ah.q[0] = *(const u64*)&sH[s0];
      ah.q[1] = *(const u64*)&sH[s0 + 4];
      al.q[0] = *(const u64*)&sH[6720 + s0];
      al.q[1] = *(const u64*)&sH[6720 + s0 + 4];
#pragma unroll
      for (int i = 0; i < 8; ++i) {
        const int jf = t - 2 * i;
        if (jf >= 0 && jf < 8) {
          acc[i] = __builtin_amdgcn_mfma_f32_16x16x32_bf16(ah.v, bhi[jf].v, acc[i], 0, 0, 0);
          acc[i] = __builtin_amdgcn_mfma_f32_16x16x32_bf16(ah.v, blo[jf].v, acc[i], 0, 0, 0);
          acc[i] = __builtin_amdgcn_mfma_f32_16x16x32_bf16(al.v, bhi[jf].v, acc[i], 0, 0, 0);
        }
      }
    }

    const int o = n & 7;
    const float bs = bias[o];
    const int px0 = x0 / 2 + 2 * g;
    const int py0 = y0w / 2;
#pragma unroll
    for (int i = 0; i < 8; ++i) {
      float v0 = fmaxf(acc[i][0], acc[i][1]);
      float v1 = fmaxf(acc[i][2], acc[i][3]);
      float p0 = __shfl_xor(v0, 8, 64);
      float p1 = __shfl_xor(v1, 8, 64);
      const int py = py0 + i;
      if (n < 8 && py < 109) {
        float m0 = fmaxf(v0, p0) + bs;
        float m1 = fmaxf(v1, p1) + bs;
        float* op = out + ((size_t)(b * 8 + o) * 109 + py) * 109 + px0;
        if (px0 < 109)     op[0] = fmaxf(m0, 0.f);
        if (px0 + 1 < 109) op[1] = fmaxf(m1, 0.f);
      }
    }
  }
}

// ---------------------------------------------------------------------------
// K2 (NEW): conv2 (8->10, 5x5) + maxpool2 + relu via MFMA 16x16x32 bf16.
// Block = 128 thr = 2 waves x 8 conv-y; tile = 8 pooled-x x 8 pooled-y.
// LDS [2 planes][20 rows][24 cols][8 c] shorts = 15.4 KB (both c-halves).
// h (c-half) looped outer, acc persistent; 5 B-pairs resident per phase.
// C/D: col = lane&15 = o, row = 4g+reg = conv-x. Pool-x in-lane (reg pairs),
// pool-y across acc pairs.
// ---------------------------------------------------------------------------
__global__ __launch_bounds__(128) void k2_mfma(
    const float* __restrict__ in, const unsigned short* __restrict__ wpHi,
    const unsigned short* __restrict__ wpLo, const float* __restrict__ bias,
    float* __restrict__ out) {
  __shared__ unsigned short sH[2 * 20 * 24 * 8];
  const int b = blockIdx.z;
  const int px0 = (blockIdx.x < 6) ? blockIdx.x * 8 : 44;
  const int py0 = (blockIdx.y < 6) ? blockIdx.y * 8 : 44;
  const int x0c = px0 * 2, y0c = py0 * 2;
  const int tid = threadIdx.x;
  const int lane = tid & 63, wid = tid >> 6;
  const int n = lane & 15, g = lane >> 4;

  // ---- stage 20x24x8 f32 -> hi/lo bf16 channels-last, two-phase
  const float* ib = in + (size_t)b * 8 * 11881;
  float v[4][8];
#pragma unroll
  for (int u = 0; u < 4; ++u) {
    int pos = tid + u * 128;
    if (pos < 480) {
      int row = pos / 24, col = pos % 24;
      int gy = y0c + row;                       // <= 107, always in bounds
      int gx = x0c + col; gx = gx < 108 ? gx : 108;  // cols >107 only hit by 0-wt
      const float* p = ib + (size_t)gy * 109 + gx;
#pragma unroll
      for (int c = 0; c < 8; ++c) v[u][c] = p[(size_t)c * 11881];
    }
  }
#pragma unroll
  for (int u = 0; u < 4; ++u) {
    int pos = tid + u * 128;
    if (pos < 480) {
      uint32_t hh[8], ll[8];
#pragma unroll
      for (int c = 0; c < 8; ++c) split1(v[u][c], hh[c], ll[c]);
      union { uint32_t w[4]; uint4 q; } H, L;
#pragma unroll
      for (int p2 = 0; p2 < 4; ++p2) {
        H.w[p2] = hh[2 * p2] | (hh[2 * p2 + 1] << 16);
        L.w[p2] = ll[2 * p2] | (ll[2 * p2 + 1] << 16);
      }
      *(uint4*)&sH[pos * 8] = H.q;
      *(uint4*)&sH[3840 + pos * 8] = L.q;
    }
  }
  __syncthreads();

  f32x4 acc[8];
#pragma unroll
  for (int i = 0; i < 8; ++i) acc[i] = (f32x4){0.f, 0.f, 0.f, 0.f};

  const int mg = n + 2 * g;
  const int rbase = wid * 8;
#pragma unroll
  for (int h = 0; h < 2; ++h) {
    BFrag bh[5], bl[5];
#pragma unroll
    for (int ky = 0; ky < 5; ++ky) {
      int idx = (((ky * 2 + h) * 4 + g) * 16 + n) * 8;
      uint4 th = *(const uint4*)&wpHi[idx];
      uint4 tl = *(const uint4*)&wpLo[idx];
      bh[ky].u[0] = th.x; bh[ky].u[1] = th.y;
      bh[ky].u[2] = th.z; bh[ky].u[3] = th.w;
      bl[ky].u[0] = tl.x; bl[ky].u[1] = tl.y;
      bl[ky].u[2] = tl.z; bl[ky].u[3] = tl.w;
    }
#pragma unroll
    for (int t = 0; t < 12; ++t) {
      const int s0 = ((rbase + t) * 24 + mg) * 8 + 4 * h;
      BFrag ah, al;
      ah.q[0] = *(const u64*)&sH[s0];
      ah.q[1] = *(const u64*)&sH[s0 + 8];
      al.q[0] = *(const u64*)&sH[3840 + s0];
      al.q[1] = *(const u64*)&sH[3840 + s0 + 8];
#pragma unroll
      for (int ky = 0; ky < 5; ++ky) {
        const int i = t - ky;
        if (i >= 0 && i < 8) {
          acc[i] = __builtin_amdgcn_mfma_f32_16x16x32_bf16(ah.v, bh[ky].v, acc[i], 0, 0, 0);
          acc[i] = __builtin_amdgcn_mfma_f32_16x16x32_bf16(ah.v, bl[ky].v, acc[i], 0, 0, 0);
          acc[i] = __builtin_amdgcn_mfma_f32_16x16x32_bf16(al.v, bh[ky].v, acc[i], 0, 0, 0);
        }
      }
    }
  }

  // ---- epilogue: pool 2x2 + bias + relu
  if (n < 10) {
    const float bs = bias[n];
    const int pxb = px0 + 2 * g;
    const int pyb = py0 + wid * 4;
#pragma unroll
    for (int u = 0; u < 4; ++u) {
      f32x4 A0 = acc[2 * u], A1 = acc[2 * u + 1];
      float m0 = fmaxf(fmaxf(A0[0], A0[1]), fmaxf(A1[0], A1[1])) + bs;
      float m1 = fmaxf(fmaxf(A0[2], A0[3]), fmaxf(A1[2], A1[3])) + bs;
      float* op = out + ((size_t)(b * 10 + n) * 52 + pyb + u) * 52 + pxb;
      op[0] = fmaxf(m0, 0.f);
      op[1] = fmaxf(m1, 0.f);
    }
  }
}

// ---------------------------------------------------------------------------
// K3: fc1 split-K partial GEMM, 256 blocks x 2 chunks of 64 (two-phase stage).
// ---------------------------------------------------------------------------
__global__ __launch_bounds__(256) void k3_fc1_partial(
    const float* __restrict__ xs, const float* __restrict__ w,
    float* __restrict__ part) {
  __shared__ float sA[128 * 64];
  __shared__ float sW[64 * 33];
  const int p = blockIdx.x;
  const int tid = threadIdx.x;
  const int n = tid & 31, bg = tid >> 5;
  float acc[16];
#pragma unroll
  for (int i = 0; i < 16; ++i) acc[i] = 0.f;

  for (int ch = 0; ch < 2; ++ch) {
    const int k0 = p * 128 + ch * 64;
    __syncthreads();
#pragma unroll
    for (int bb = 0; bb < 4; ++bb) {
      float v[8];
#pragma unroll
      for (int u = 0; u < 8; ++u) {
        int idx = bb * 2048 + u * 256 + tid;
        int bbv = idx >> 6, k = idx & 63;
        int gk = k0 + k;
        v[u] = (gk < 27040) ? xs[bbv * 27040 + gk] : 0.f;
      }
#pragma unroll
      for (int u = 0; u < 8; ++u) {
        int idx = bb * 2048 + u * 256 + tid;
        sA[idx] = v[u];
      }
    }
    {
      float v[8];
#pragma unroll
      for (int u = 0; u < 8; ++u) {
        int idx = u * 256 + tid;
        int nn = idx >> 6, k = idx & 63;
        int gk = k0 + k;
        v[u] = (gk < 27040) ? w[nn * 27040 + gk] : 0.f;
      }
#pragma unroll
      for (int u = 0; u < 8; ++u) {
        int idx = u * 256 + tid;
        int nn = idx >> 6, k = idx & 63;
        sW[k * 33 + nn] = v[u];
      }
    }
    __syncthreads();
    for (int k = 0; k < 64; k += 4) {
      float w0 = sW[(k + 0) * 33 + n];
      float w1 = sW[(k + 1) * 33 + n];
      float w2 = sW[(k + 2) * 33 + n];
      float w3 = sW[(k + 3) * 33 + n];
#pragma unroll
      for (int i = 0; i < 16; ++i) {
        float4 a = *(const float4*)&sA[(bg * 16 + i) * 64 + k];
        acc[i] = fmaf(a.x, w0, acc[i]);
        acc[i] = fmaf(a.y, w1, acc[i]);
        acc[i] = fmaf(a.z, w2, acc[i]);
        acc[i] = fmaf(a.w, w3, acc[i]);
      }
    }
  }
#pragma unroll
  for (int i = 0; i < 16; ++i)
    part[p * 4096 + (bg * 16 + i) * 32 + n] = acc[i];
}

// ---------------------------------------------------------------------------
// K4: reduce 256 partials -> h = relu(C + b1). 512 blocks, shfl-reduce.
// ---------------------------------------------------------------------------
__global__ __launch_bounds__(256) void k4_reduce(
    const float* __restrict__ part, const float* __restrict__ b1,
    float* __restrict__ h) {
  const int lane = threadIdx.x & 31;
  const int eloc = threadIdx.x >> 5;
  const int e = blockIdx.x * 8 + eloc;
  float s = 0.f;
#pragma unroll
  for (int pc = 0; pc < 8; ++pc) s += part[(pc * 32 + lane) * 4096 + e];
#pragma unroll
  for (int off = 16; off > 0; off >>= 1) s += __shfl_down(s, off, 32);
  if (lane == 0) h[e] = fmaxf(s + b1[e & 31], 0.f);
}

// ---------------------------------------------------------------------------
// K5: theta (recomputed per block) + fused affine_grid + bilinear sample.
// ---------------------------------------------------------------------------
__global__ __launch_bounds__(256) void k5_sample(
    const float* __restrict__ x, const float* __restrict__ h,
    const float* __restrict__ w2, const float* __restrict__ b2,
    float* __restrict__ out) {
  __shared__ float th[6];
  const int b = blockIdx.z;
  if (threadIdx.x < 6) {
    int j = threadIdx.x;
    float s = b2[j];
    for (int m = 0; m < 32; ++m) s = fmaf(h[b * 32 + m], w2[j * 32 + m], s);
    th[j] = s;
  }
  __syncthreads();

  const int pix = blockIdx.x * 256 + threadIdx.x;
  const int hh = pix / 224, ww = pix % 224;
  const float step = 2.0f / 223.0f;
  float gx = ww * step - 1.0f, gy = hh * step - 1.0f;
  float tx = th[0] * gx + th[1] * gy + th[2];
  float ty = th[3] * gx + th[4] * gy + th[5];
  float ix = (tx + 1.0f) * 0.5f * 223.0f;
  float iy = (ty + 1.0f) * 0.5f * 223.0f;
  float x0 = floorf(ix), y0 = floorf(iy);
  float x1 = x0 + 1.f, y1 = y0 + 1.f;
  float wx1 = ix - x0, wx0 = x1 - ix;
  float wy1 = iy - y0, wy0 = y1 - iy;
  float w00 = wx0 * wy0, w01 = wx1 * wy0, w10 = wx0 * wy1, w11 = wx1 * wy1;
  bool vx0 = (x0 >= 0.f) && (x0 <= 223.f);
  bool vx1 = (x1 >= 0.f) && (x1 <= 223.f);
  bool vy0 = (y0 >= 0.f) && (y0 <= 223.f);
  bool vy1 = (y1 >= 0.f) && (y1 <= 223.f);
  w00 = (vx0 && vy0) ? w00 : 0.f;
  w01 = (vx1 && vy0) ? w01 : 0.f;
  w10 = (vx0 && vy1) ? w10 : 0.f;
  w11 = (vx1 && vy1) ? w11 : 0.f;
  int xi0 = (int)fminf(fmaxf(x0, 0.f), 223.f);
  int xi1 = (int)fminf(fmaxf(x1, 0.f), 223.f);
  int yi0 = (int)fminf(fmaxf(y0, 0.f), 223.f);
  int yi1 = (int)fminf(fmaxf(y1, 0.f), 223.f);
#pragma unroll
  for (int c = 0; c < 3; ++c) {
    const float* img = x + (size_t)((b * 3 + c) * 224) * 224;
    float v = img[yi0 * 224 + xi0] * w00 + img[yi0 * 224 + xi1] * w01 +
              img[yi1 * 224 + xi0] * w10 + img[yi1 * 224 + xi1] * w11;
    out[((b * 3 + c) * 224 + hh) * 224 + ww] = v;
  }
}

extern "C" void kernel_launch(void* const* d_in, const int* in_sizes, int n_in,
                              void* d_out, int out_size, void* d_ws,
                              size_t ws_size, hipStream_t stream) {
  const float* x   = (const float*)d_in[0];
  const float* w1  = (const float*)d_in[1];
  const float* b1  = (const float*)d_in[2];
  const float* w2  = (const float*)d_in[3];
  const float* b2  = (const float*)d_in[4];
  const float* fw1 = (const float*)d_in[5];
  const float* fb1 = (const float*)d_in[6];
  const float* fw2 = (const float*)d_in[7];
  const float* fb2 = (const float*)d_in[8];
  float* out = (float*)d_out;

  float* ws   = (float*)d_ws;
  float* out1 = ws;                    // [128,8,109,109] = 12,166,144 f32
  float* xs   = out1 + 12166144;       // [128,10,52,52]  =  3,461,120 f32
  float* part = xs + 3461120;          // [256,128,32]    =  1,048,576 f32
  float* hbuf = part + 1048576;        // [128,32]        =      4,096 f32
  unsigned short* wpHi  = (unsigned short*)(hbuf + 4096);  // 4096 us
  unsigned short* wpLo  = wpHi + 4096;                     // 4096 us
  unsigned short* wp2Hi = wpLo + 4096;                     // 5120 us
  unsigned short* wp2Lo = wp2Hi + 5120;                    // 5120 us

  k0_wprep<<<16, 256, 0, stream>>>(w1, wpHi, wpLo);
  k0b_wprep<<<20, 256, 0, stream>>>(w2, wp2Hi, wp2Lo);
  k1_mfma<<<dim3(14, 4, 128), 256, 0, stream>>>(x, wpHi, wpLo, b1, out1);
  k2_mfma<<<dim3(7, 7, 128), 128, 0, stream>>>(out1, wp2Hi, wp2Lo, b2, xs);
  k3_fc1_partial<<<256, 256, 0, stream>>>(xs, fw1, part);
  k4_reduce<<<512, 256, 0, stream>>>(part, fb1, hbuf);
  k5_sample<<<dim3(196, 1, 128), 256, 0, stream>>>(x, hbuf, fw2, fb2, out);
}

// Round 13
// 209.760 us; speedup vs baseline: 1.3075x; 1.0794x over previous
//
#include <hip/hip_runtime.h>
#include <hip/hip_bf16.h>
#include <stdint.h>

typedef __bf16 bf16x8 __attribute__((ext_vector_type(8)));
typedef float f32x4 __attribute__((ext_vector_type(4)));
typedef unsigned long long u64;

union BFrag { uint32_t u[4]; u64 q[2]; bf16x8 v; };

// truncation split: f = hi + lo (+ O(2^-17) on lo)
__device__ __forceinline__ void split1(float f, uint32_t& hi, uint32_t& lo) {
  uint32_t b = __float_as_uint(f);
  hi = b >> 16;
  float fl = f - __uint_as_float(b & 0xFFFF0000u);
  lo = __float_as_uint(fl) >> 16;
}

// ---------------------------------------------------------------------------
// K0: pack conv1 weights into MFMA B-fragments (hi/lo bf16).
// ---------------------------------------------------------------------------
__global__ __launch_bounds__(256) void k0_wprep(
    const float* __restrict__ w1, unsigned short* __restrict__ wpHi,
    unsigned short* __restrict__ wpLo) {
  int id = blockIdx.x * 256 + threadIdx.x;
  if (id >= 4096) return;
  int j = id & 7, n = (id >> 3) & 15, g = (id >> 7) & 3, jf = id >> 9;
  int o = n & 7, half = n >> 3;
  int ky = jf - half, c = j & 3, kx = 2 * g + (j >> 2);
  float f = 0.f;
  if (c < 3 && kx < 7 && ky >= 0 && ky < 7)
    f = w1[o * 147 + c * 49 + ky * 7 + kx];
  uint32_t h, l;
  split1(f, h, l);
  wpHi[id] = (unsigned short)h;
  wpLo[id] = (unsigned short)l;
}

// ---------------------------------------------------------------------------
// K0b: pack conv2 weights. id = ((hk*4+g)*16 + n)*8 + j, hk = ky*2+h.
// ---------------------------------------------------------------------------
__global__ __launch_bounds__(256) void k0b_wprep(
    const float* __restrict__ w2, unsigned short* __restrict__ wpHi,
    unsigned short* __restrict__ wpLo) {
  int id = blockIdx.x * 256 + threadIdx.x;
  if (id >= 5120) return;
  int j = id & 7, n = (id >> 3) & 15, g = (id >> 7) & 3;
  int hk = id >> 9;
  int h = hk & 1, ky = hk >> 1;
  int c = 4 * h + (j & 3), kx = 2 * g + (j >> 2);
  float f = 0.f;
  if (n < 10 && kx < 5)
    f = w2[n * 200 + c * 25 + ky * 5 + kx];
  uint32_t hh, ll;
  split1(f, hh, ll);
  wpHi[id] = (unsigned short)hh;
  wpLo[id] = (unsigned short)ll;
}

// ---------------------------------------------------------------------------
// K1: conv1 + maxpool2 + relu, MFMA 16x16x32 bf16 (R10 core).
// NEW: out1 written CHANNELS-LAST [b][109][109][8] -> coalesced 256B stores.
// ---------------------------------------------------------------------------
__global__ __launch_bounds__(256) void k1_mfma(
    const float* __restrict__ x, const unsigned short* __restrict__ wpHi,
    const unsigned short* __restrict__ wpLo, const float* __restrict__ bias,
    float* __restrict__ out) {
  __shared__ unsigned short sH[2 * 70 * 24 * 4];
  const int b = blockIdx.z;
  const int x0 = blockIdx.x * 16;
  const int y0blk = blockIdx.y * 64;
  const int tid = threadIdx.x;
  const int lane = tid & 63, wid = tid >> 6;
  const int n = lane & 15, g = lane >> 4;

  BFrag bhi[8], blo[8];
#pragma unroll
  for (int jf = 0; jf < 8; ++jf) {
    uint4 th = *(const uint4*)&wpHi[((jf * 4 + g) * 16 + n) * 8];
    uint4 tl = *(const uint4*)&wpLo[((jf * 4 + g) * 16 + n) * 8];
    bhi[jf].u[0] = th.x; bhi[jf].u[1] = th.y;
    bhi[jf].u[2] = th.z; bhi[jf].u[3] = th.w;
    blo[jf].u[0] = tl.x; blo[jf].u[1] = tl.y;
    blo[jf].u[2] = tl.z; blo[jf].u[3] = tl.w;
  }

  const float* xb = x + (size_t)b * 3 * 50176;
  float pv0[7], pv1[7], pv2[7];
#pragma unroll
  for (int u = 0; u < 7; ++u) {
    int pos = tid + u * 256;
    if (pos < 1680) {
      int row = pos / 24, col = pos % 24;
      int gy = y0blk + row; gy = gy < 223 ? gy : 223;
      int gx = x0 + col;    gx = gx < 223 ? gx : 223;
      const float* p = xb + (size_t)gy * 224 + gx;
      pv0[u] = p[0];
      pv1[u] = p[50176];
      pv2[u] = p[100352];
    }
  }
#pragma unroll
  for (int u = 0; u < 7; ++u) {
    int pos = tid + u * 256;
    if (pos < 1680) {
      uint32_t h0, l0, h1, l1, h2, l2;
      split1(pv0[u], h0, l0);
      split1(pv1[u], h1, l1);
      split1(pv2[u], h2, l2);
      u64 hq = (u64)(h0 | (h1 << 16)) | ((u64)h2 << 32);
      u64 lq = (u64)(l0 | (l1 << 16)) | ((u64)l2 << 32);
      *(u64*)&sH[pos * 4] = hq;
      *(u64*)&sH[6720 + pos * 4] = lq;
    }
  }
  __syncthreads();

  const int y0w = y0blk + wid * 16;
  if (y0w <= 217) {
    f32x4 acc[8];
#pragma unroll
    for (int i = 0; i < 8; ++i) acc[i] = (f32x4){0.f, 0.f, 0.f, 0.f};

    const int mg = n + 2 * g;
    const int rbase = wid * 16;
#pragma unroll
    for (int t = 0; t < 22; ++t) {
      const int s0 = ((rbase + t) * 24 + mg) * 4;
      BFrag ah, al;
      ah.q[0] = *(const u64*)&sH[s0];
      ah.q[1] = *(const u64*)&sH[s0 + 4];
      al.q[0] = *(const u64*)&sH[6720 + s0];
      al.q[1] = *(const u64*)&sH[6720 + s0 + 4];
#pragma unroll
      for (int i = 0; i < 8; ++i) {
        const int jf = t - 2 * i;
        if (jf >= 0 && jf < 8) {
          acc[i] = __builtin_amdgcn_mfma_f32_16x16x32_bf16(ah.v, bhi[jf].v, acc[i], 0, 0, 0);
          acc[i] = __builtin_amdgcn_mfma_f32_16x16x32_bf16(ah.v, blo[jf].v, acc[i], 0, 0, 0);
          acc[i] = __builtin_amdgcn_mfma_f32_16x16x32_bf16(al.v, bhi[jf].v, acc[i], 0, 0, 0);
        }
      }
    }

    // ---- epilogue: pool-x in-lane, pool-y via shfl_xor(8); channels-last out
    const int o = n & 7;
    const float bs = bias[o];
    const int px0 = x0 / 2 + 2 * g;
    const int py0 = y0w / 2;
#pragma unroll
    for (int i = 0; i < 8; ++i) {
      float v0 = fmaxf(acc[i][0], acc[i][1]);
      float v1 = fmaxf(acc[i][2], acc[i][3]);
      float p0 = __shfl_xor(v0, 8, 64);
      float p1 = __shfl_xor(v1, 8, 64);
      const int py = py0 + i;
      if (n < 8 && py < 109) {
        float m0 = fmaxf(v0, p0) + bs;
        float m1 = fmaxf(v1, p1) + bs;
        float* op = out + (((size_t)(b * 109 + py)) * 109 + px0) * 8 + o;
        if (px0 < 109)     op[0] = fmaxf(m0, 0.f);
        if (px0 + 1 < 109) op[8] = fmaxf(m1, 0.f);
      }
    }
  }
}

// ---------------------------------------------------------------------------
// K2: conv2 + maxpool2 + relu via MFMA 16x16x32 bf16.
// NEW: input read from channels-last out1 -> 2x float4 per pixel, coalesced.
// ---------------------------------------------------------------------------
__global__ __launch_bounds__(128) void k2_mfma(
    const float* __restrict__ in, const unsigned short* __restrict__ wpHi,
    const unsigned short* __restrict__ wpLo, const float* __restrict__ bias,
    float* __restrict__ out) {
  __shared__ unsigned short sH[2 * 20 * 24 * 8];
  const int b = blockIdx.z;
  const int px0 = (blockIdx.x < 6) ? blockIdx.x * 8 : 44;
  const int py0 = (blockIdx.y < 6) ? blockIdx.y * 8 : 44;
  const int x0c = px0 * 2, y0c = py0 * 2;
  const int tid = threadIdx.x;
  const int lane = tid & 63, wid = tid >> 6;
  const int n = lane & 15, g = lane >> 4;

  // ---- stage 20x24x8 f32 (channels-last) -> hi/lo bf16, two-phase
  const float* ib = in + (size_t)b * 109 * 109 * 8;
  float v[4][8];
#pragma unroll
  for (int u = 0; u < 4; ++u) {
    int pos = tid + u * 128;
    if (pos < 480) {
      int row = pos / 24, col = pos % 24;
      int gy = y0c + row;
      int gx = x0c + col; gx = gx < 108 ? gx : 108;
      const float* p = ib + ((size_t)gy * 109 + gx) * 8;
      float4 q0 = *(const float4*)p;
      float4 q1 = *(const float4*)(p + 4);
      v[u][0] = q0.x; v[u][1] = q0.y; v[u][2] = q0.z; v[u][3] = q0.w;
      v[u][4] = q1.x; v[u][5] = q1.y; v[u][6] = q1.z; v[u][7] = q1.w;
    }
  }
#pragma unroll
  for (int u = 0; u < 4; ++u) {
    int pos = tid + u * 128;
    if (pos < 480) {
      uint32_t hh[8], ll[8];
#pragma unroll
      for (int c = 0; c < 8; ++c) split1(v[u][c], hh[c], ll[c]);
      union { uint32_t w[4]; uint4 q; } H, L;
#pragma unroll
      for (int p2 = 0; p2 < 4; ++p2) {
        H.w[p2] = hh[2 * p2] | (hh[2 * p2 + 1] << 16);
        L.w[p2] = ll[2 * p2] | (ll[2 * p2 + 1] << 16);
      }
      *(uint4*)&sH[pos * 8] = H.q;
      *(uint4*)&sH[3840 + pos * 8] = L.q;
    }
  }
  __syncthreads();

  f32x4 acc[8];
#pragma unroll
  for (int i = 0; i < 8; ++i) acc[i] = (f32x4){0.f, 0.f, 0.f, 0.f};

  const int mg = n + 2 * g;
  const int rbase = wid * 8;
#pragma unroll
  for (int h = 0; h < 2; ++h) {
    BFrag bh[5], bl[5];
#pragma unroll
    for (int ky = 0; ky < 5; ++ky) {
      int idx = (((ky * 2 + h) * 4 + g) * 16 + n) * 8;
      uint4 th = *(const uint4*)&wpHi[idx];
      uint4 tl = *(const uint4*)&wpLo[idx];
      bh[ky].u[0] = th.x; bh[ky].u[1] = th.y;
      bh[ky].u[2] = th.z; bh[ky].u[3] = th.w;
      bl[ky].u[0] = tl.x; bl[ky].u[1] = tl.y;
      bl[ky].u[2] = tl.z; bl[ky].u[3] = tl.w;
    }
#pragma unroll
    for (int t = 0; t < 12; ++t) {
      const int s0 = ((rbase + t) * 24 + mg) * 8 + 4 * h;
      BFrag ah, al;
      ah.q[0] = *(const u64*)&sH[s0];
      ah.q[1] = *(const u64*)&sH[s0 + 8];
      al.q[0] = *(const u64*)&sH[3840 + s0];
      al.q[1] = *(const u64*)&sH[3840 + s0 + 8];
#pragma unroll
      for (int ky = 0; ky < 5; ++ky) {
        const int i = t - ky;
        if (i >= 0 && i < 8) {
          acc[i] = __builtin_amdgcn_mfma_f32_16x16x32_bf16(ah.v, bh[ky].v, acc[i], 0, 0, 0);
          acc[i] = __builtin_amdgcn_mfma_f32_16x16x32_bf16(ah.v, bl[ky].v, acc[i], 0, 0, 0);
          acc[i] = __builtin_amdgcn_mfma_f32_16x16x32_bf16(al.v, bh[ky].v, acc[i], 0, 0, 0);
        }
      }
    }
  }

  if (n < 10) {
    const float bs = bias[n];
    const int pxb = px0 + 2 * g;
    const int pyb = py0 + wid * 4;
#pragma unroll
    for (int u = 0; u < 4; ++u) {
      f32x4 A0 = acc[2 * u], A1 = acc[2 * u + 1];
      float m0 = fmaxf(fmaxf(A0[0], A0[1]), fmaxf(A1[0], A1[1])) + bs;
      float m1 = fmaxf(fmaxf(A0[2], A0[3]), fmaxf(A1[2], A1[3])) + bs;
      float* op = out + ((size_t)(b * 10 + n) * 52 + pyb + u) * 52 + pxb;
      op[0] = fmaxf(m0, 0.f);
      op[1] = fmaxf(m1, 0.f);
    }
  }
}

// ---------------------------------------------------------------------------
// K3: fc1 split-K partial GEMM, 256 blocks x 2 chunks of 64 (two-phase stage).
// ---------------------------------------------------------------------------
__global__ __launch_bounds__(256) void k3_fc1_partial(
    const float* __restrict__ xs, const float* __restrict__ w,
    float* __restrict__ part) {
  __shared__ float sA[128 * 64];
  __shared__ float sW[64 * 33];
  const int p = blockIdx.x;
  const int tid = threadIdx.x;
  const int n = tid & 31, bg = tid >> 5;
  float acc[16];
#pragma unroll
  for (int i = 0; i < 16; ++i) acc[i] = 0.f;

  for (int ch = 0; ch < 2; ++ch) {
    const int k0 = p * 128 + ch * 64;
    __syncthreads();
#pragma unroll
    for (int bb = 0; bb < 4; ++bb) {
      float v[8];
#pragma unroll
      for (int u = 0; u < 8; ++u) {
        int idx = bb * 2048 + u * 256 + tid;
        int bbv = idx >> 6, k = idx & 63;
        int gk = k0 + k;
        v[u] = (gk < 27040) ? xs[bbv * 27040 + gk] : 0.f;
      }
#pragma unroll
      for (int u = 0; u < 8; ++u) {
        int idx = bb * 2048 + u * 256 + tid;
        sA[idx] = v[u];
      }
    }
    {
      float v[8];
#pragma unroll
      for (int u = 0; u < 8; ++u) {
        int idx = u * 256 + tid;
        int nn = idx >> 6, k = idx & 63;
        int gk = k0 + k;
        v[u] = (gk < 27040) ? w[nn * 27040 + gk] : 0.f;
      }
#pragma unroll
      for (int u = 0; u < 8; ++u) {
        int idx = u * 256 + tid;
        int nn = idx >> 6, k = idx & 63;
        sW[k * 33 + nn] = v[u];
      }
    }
    __syncthreads();
    for (int k = 0; k < 64; k += 4) {
      float w0 = sW[(k + 0) * 33 + n];
      float w1 = sW[(k + 1) * 33 + n];
      float w2 = sW[(k + 2) * 33 + n];
      float w3 = sW[(k + 3) * 33 + n];
#pragma unroll
      for (int i = 0; i < 16; ++i) {
        float4 a = *(const float4*)&sA[(bg * 16 + i) * 64 + k];
        acc[i] = fmaf(a.x, w0, acc[i]);
        acc[i] = fmaf(a.y, w1, acc[i]);
        acc[i] = fmaf(a.z, w2, acc[i]);
        acc[i] = fmaf(a.w, w3, acc[i]);
      }
    }
  }
#pragma unroll
  for (int i = 0; i < 16; ++i)
    part[p * 4096 + (bg * 16 + i) * 32 + n] = acc[i];
}

// ---------------------------------------------------------------------------
// K4: reduce 256 partials -> h = relu(C + b1). 512 blocks, shfl-reduce.
// ---------------------------------------------------------------------------
__global__ __launch_bounds__(256) void k4_reduce(
    const float* __restrict__ part, const float* __restrict__ b1,
    float* __restrict__ h) {
  const int lane = threadIdx.x & 31;
  const int eloc = threadIdx.x >> 5;
  const int e = blockIdx.x * 8 + eloc;
  float s = 0.f;
#pragma unroll
  for (int pc = 0; pc < 8; ++pc) s += part[(pc * 32 + lane) * 4096 + e];
#pragma unroll
  for (int off = 16; off > 0; off >>= 1) s += __shfl_down(s, off, 32);
  if (lane == 0) h[e] = fmaxf(s + b1[e & 31], 0.f);
}

// ---------------------------------------------------------------------------
// K5: theta (recomputed per block) + fused affine_grid + bilinear sample.
// ---------------------------------------------------------------------------
__global__ __launch_bounds__(256) void k5_sample(
    const float* __restrict__ x, const float* __restrict__ h,
    const float* __restrict__ w2, const float* __restrict__ b2,
    float* __restrict__ out) {
  __shared__ float th[6];
  const int b = blockIdx.z;
  if (threadIdx.x < 6) {
    int j = threadIdx.x;
    float s = b2[j];
    for (int m = 0; m < 32; ++m) s = fmaf(h[b * 32 + m], w2[j * 32 + m], s);
    th[j] = s;
  }
  __syncthreads();

  const int pix = blockIdx.x * 256 + threadIdx.x;
  const int hh = pix / 224, ww = pix % 224;
  const float step = 2.0f / 223.0f;
  float gx = ww * step - 1.0f, gy = hh * step - 1.0f;
  float tx = th[0] * gx + th[1] * gy + th[2];
  float ty = th[3] * gx + th[4] * gy + th[5];
  float ix = (tx + 1.0f) * 0.5f * 223.0f;
  float iy = (ty + 1.0f) * 0.5f * 223.0f;
  float x0 = floorf(ix), y0 = floorf(iy);
  float x1 = x0 + 1.f, y1 = y0 + 1.f;
  float wx1 = ix - x0, wx0 = x1 - ix;
  float wy1 = iy - y0, wy0 = y1 - iy;
  float w00 = wx0 * wy0, w01 = wx1 * wy0, w10 = wx0 * wy1, w11 = wx1 * wy1;
  bool vx0 = (x0 >= 0.f) && (x0 <= 223.f);
  bool vx1 = (x1 >= 0.f) && (x1 <= 223.f);
  bool vy0 = (y0 >= 0.f) && (y0 <= 223.f);
  bool vy1 = (y1 >= 0.f) && (y1 <= 223.f);
  w00 = (vx0 && vy0) ? w00 : 0.f;
  w01 = (vx1 && vy0) ? w01 : 0.f;
  w10 = (vx0 && vy1) ? w10 : 0.f;
  w11 = (vx1 && vy1) ? w11 : 0.f;
  int xi0 = (int)fminf(fmaxf(x0, 0.f), 223.f);
  int xi1 = (int)fminf(fmaxf(x1, 0.f), 223.f);
  int yi0 = (int)fminf(fmaxf(y0, 0.f), 223.f);
  int yi1 = (int)fminf(fmaxf(y1, 0.f), 223.f);
#pragma unroll
  for (int c = 0; c < 3; ++c) {
    const float* img = x + (size_t)((b * 3 + c) * 224) * 224;
    float v = img[yi0 * 224 + xi0] * w00 + img[yi0 * 224 + xi1] * w01 +
              img[yi1 * 224 + xi0] * w10 + img[yi1 * 224 + xi1] * w11;
    out[((b * 3 + c) * 224 + hh) * 224 + ww] = v;
  }
}

extern "C" void kernel_launch(void* const* d_in, const int* in_sizes, int n_in,
                              void* d_out, int out_size, void* d_ws,
                              size_t ws_size, hipStream_t stream) {
  const float* x   = (const float*)d_in[0];
  const float* w1  = (const float*)d_in[1];
  const float* b1  = (const float*)d_in[2];
  const float* w2  = (const float*)d_in[3];
  const float* b2  = (const float*)d_in[4];
  const float* fw1 = (const float*)d_in[5];
  const float* fb1 = (const float*)d_in[6];
  const float* fw2 = (const float*)d_in[7];
  const float* fb2 = (const float*)d_in[8];
  float* out = (float*)d_out;

  float* ws   = (float*)d_ws;
  float* out1 = ws;                    // [128,109,109,8] ch-last = 12,166,144
  float* xs   = out1 + 12166144;       // [128,10,52,52]  =  3,461,120 f32
  float* part = xs + 3461120;          // [256,128,32]    =  1,048,576 f32
  float* hbuf = part + 1048576;        // [128,32]        =      4,096 f32
  unsigned short* wpHi  = (unsigned short*)(hbuf + 4096);  // 4096 us
  unsigned short* wpLo  = wpHi + 4096;                     // 4096 us
  unsigned short* wp2Hi = wpLo + 4096;                     // 5120 us
  unsigned short* wp2Lo = wp2Hi + 5120;                    // 5120 us

  k0_wprep<<<16, 256, 0, stream>>>(w1, wpHi, wpLo);
  k0b_wprep<<<20, 256, 0, stream>>>(w2, wp2Hi, wp2Lo);
  k1_mfma<<<dim3(14, 4, 128), 256, 0, stream>>>(x, wpHi, wpLo, b1, out1);
  k2_mfma<<<dim3(7, 7, 128), 128, 0, stream>>>(out1, wp2Hi, wp2Lo, b2, xs);
  k3_fc1_partial<<<256, 256, 0, stream>>>(xs, fw1, part);
  k4_reduce<<<512, 256, 0, stream>>>(part, fb1, hbuf);
  k5_sample<<<dim3(196, 1, 128), 256, 0, stream>>>(x, hbuf, fw2, fb2, out);
}

// Round 14
// 200.195 us; speedup vs baseline: 1.3700x; 1.0478x over previous
//
#include <hip/hip_runtime.h>
#include <hip/hip_bf16.h>
#include <stdint.h>

typedef __bf16 bf16x8 __attribute__((ext_vector_type(8)));
typedef float f32x4 __attribute__((ext_vector_type(4)));
typedef unsigned long long u64;

union BFrag { uint32_t u[4]; u64 q[2]; bf16x8 v; };

// truncation split: f = hi + lo (+ O(2^-17) on lo)
__device__ __forceinline__ void split1(float f, uint32_t& hi, uint32_t& lo) {
  uint32_t b = __float_as_uint(f);
  hi = b >> 16;
  float fl = f - __uint_as_float(b & 0xFFFF0000u);
  lo = __float_as_uint(fl) >> 16;
}

// ---------------------------------------------------------------------------
// K0 (merged): pack conv1 AND conv2 weights into MFMA B-fragment tables.
// ---------------------------------------------------------------------------
__global__ __launch_bounds__(256) void k0_wprep(
    const float* __restrict__ w1, const float* __restrict__ w2,
    unsigned short* __restrict__ wpHi, unsigned short* __restrict__ wpLo,
    unsigned short* __restrict__ wp2Hi, unsigned short* __restrict__ wp2Lo) {
  int id = blockIdx.x * 256 + threadIdx.x;
  if (id < 4096) {
    int j = id & 7, n = (id >> 3) & 15, g = (id >> 7) & 3, jf = id >> 9;
    int o = n & 7, half = n >> 3;
    int ky = jf - half, c = j & 3, kx = 2 * g + (j >> 2);
    float f = 0.f;
    if (c < 3 && kx < 7 && ky >= 0 && ky < 7)
      f = w1[o * 147 + c * 49 + ky * 7 + kx];
    uint32_t h, l;
    split1(f, h, l);
    wpHi[id] = (unsigned short)h;
    wpLo[id] = (unsigned short)l;
  }
  if (id < 5120) {
    int j = id & 7, n = (id >> 3) & 15, g = (id >> 7) & 3;
    int hk = id >> 9;
    int h = hk & 1, ky = hk >> 1;
    int c = 4 * h + (j & 3), kx = 2 * g + (j >> 2);
    float f = 0.f;
    if (n < 10 && kx < 5)
      f = w2[n * 200 + c * 25 + ky * 5 + kx];
    uint32_t hh, ll;
    split1(f, hh, ll);
    wp2Hi[id] = (unsigned short)hh;
    wp2Lo[id] = (unsigned short)ll;
  }
}

// ---------------------------------------------------------------------------
// K1 v4: conv1 + maxpool2 + relu, MFMA 16x16x32 bf16.
// 32-wide x-tile, 512 thr = 8 waves (xh = wid&1 x-subtile, yq = wid>>1).
// Halo read amp 1.5 -> 1.25; half the blocks. Channels-last output.
// ---------------------------------------------------------------------------
__global__ __launch_bounds__(512) void k1_mfma(
    const float* __restrict__ x, const unsigned short* __restrict__ wpHi,
    const unsigned short* __restrict__ wpLo, const float* __restrict__ bias,
    float* __restrict__ out) {
  __shared__ unsigned short sH[2 * 70 * 40 * 4];  // 44.8 KB
  const int b = blockIdx.z;
  const int x0 = blockIdx.x * 32;
  const int y0blk = blockIdx.y * 64;
  const int tid = threadIdx.x;
  const int lane = tid & 63, wid = tid >> 6;
  const int n = lane & 15, g = lane >> 4;
  const int xh = wid & 1, yq = wid >> 1;

  BFrag bhi[8], blo[8];
#pragma unroll
  for (int jf = 0; jf < 8; ++jf) {
    uint4 th = *(const uint4*)&wpHi[((jf * 4 + g) * 16 + n) * 8];
    uint4 tl = *(const uint4*)&wpLo[((jf * 4 + g) * 16 + n) * 8];
    bhi[jf].u[0] = th.x; bhi[jf].u[1] = th.y;
    bhi[jf].u[2] = th.z; bhi[jf].u[3] = th.w;
    blo[jf].u[0] = tl.x; blo[jf].u[1] = tl.y;
    blo[jf].u[2] = tl.z; blo[jf].u[3] = tl.w;
  }

  // ---- two-phase staging: 70 rows x 40 cols x 3 ch
  const float* xb = x + (size_t)b * 3 * 50176;
  float pv0[6], pv1[6], pv2[6];
#pragma unroll
  for (int u = 0; u < 6; ++u) {
    int pos = tid + u * 512;
    if (pos < 2800) {
      int row = pos / 40, col = pos % 40;
      int gy = y0blk + row; gy = gy < 223 ? gy : 223;
      int gx = x0 + col;    gx = gx < 223 ? gx : 223;
      const float* p = xb + (size_t)gy * 224 + gx;
      pv0[u] = p[0];
      pv1[u] = p[50176];
      pv2[u] = p[100352];
    }
  }
#pragma unroll
  for (int u = 0; u < 6; ++u) {
    int pos = tid + u * 512;
    if (pos < 2800) {
      uint32_t h0, l0, h1, l1, h2, l2;
      split1(pv0[u], h0, l0);
      split1(pv1[u], h1, l1);
      split1(pv2[u], h2, l2);
      u64 hq = (u64)(h0 | (h1 << 16)) | ((u64)h2 << 32);
      u64 lq = (u64)(l0 | (l1 << 16)) | ((u64)l2 << 32);
      *(u64*)&sH[pos * 4] = hq;            // hi plane
      *(u64*)&sH[11200 + pos * 4] = lq;    // lo plane
    }
  }
  __syncthreads();

  const int y0w = y0blk + yq * 16;
  if (y0w <= 217) {
    f32x4 acc[8];
#pragma unroll
    for (int i = 0; i < 8; ++i) acc[i] = (f32x4){0.f, 0.f, 0.f, 0.f};

    const int mg = xh * 16 + n + 2 * g;
    const int rbase = yq * 16;
#pragma unroll
    for (int t = 0; t < 22; ++t) {
      const int s0 = ((rbase + t) * 40 + mg) * 4;
      BFrag ah, al;
      ah.q[0] = *(const u64*)&sH[s0];
      ah.q[1] = *(const u64*)&sH[s0 + 4];
      al.q[0] = *(const u64*)&sH[11200 + s0];
      al.q[1] = *(const u64*)&sH[11200 + s0 + 4];
#pragma unroll
      for (int i = 0; i < 8; ++i) {
        const int jf = t - 2 * i;
        if (jf >= 0 && jf < 8) {
          acc[i] = __builtin_amdgcn_mfma_f32_16x16x32_bf16(ah.v, bhi[jf].v, acc[i], 0, 0, 0);
          acc[i] = __builtin_amdgcn_mfma_f32_16x16x32_bf16(ah.v, blo[jf].v, acc[i], 0, 0, 0);
          acc[i] = __builtin_amdgcn_mfma_f32_16x16x32_bf16(al.v, bhi[jf].v, acc[i], 0, 0, 0);
        }
      }
    }

    // ---- epilogue: pool-x in-lane, pool-y via shfl_xor(8); channels-last
    const int o = n & 7;
    const float bs = bias[o];
    const int px0 = x0 / 2 + xh * 8 + 2 * g;
    const int py0 = y0w / 2;
#pragma unroll
    for (int i = 0; i < 8; ++i) {
      float v0 = fmaxf(acc[i][0], acc[i][1]);
      float v1 = fmaxf(acc[i][2], acc[i][3]);
      float p0 = __shfl_xor(v0, 8, 64);
      float p1 = __shfl_xor(v1, 8, 64);
      const int py = py0 + i;
      if (n < 8 && py < 109) {
        float m0 = fmaxf(v0, p0) + bs;
        float m1 = fmaxf(v1, p1) + bs;
        float* op = out + (((size_t)(b * 109 + py)) * 109 + px0) * 8 + o;
        if (px0 < 109)     op[0] = fmaxf(m0, 0.f);
        if (px0 + 1 < 109) op[8] = fmaxf(m1, 0.f);
      }
    }
  }
}

// ---------------------------------------------------------------------------
// K2: conv2 + maxpool2 + relu via MFMA 16x16x32 bf16 (channels-last input).
// ---------------------------------------------------------------------------
__global__ __launch_bounds__(128) void k2_mfma(
    const float* __restrict__ in, const unsigned short* __restrict__ wpHi,
    const unsigned short* __restrict__ wpLo, const float* __restrict__ bias,
    float* __restrict__ out) {
  __shared__ unsigned short sH[2 * 20 * 24 * 8];
  const int b = blockIdx.z;
  const int px0 = (blockIdx.x < 6) ? blockIdx.x * 8 : 44;
  const int py0 = (blockIdx.y < 6) ? blockIdx.y * 8 : 44;
  const int x0c = px0 * 2, y0c = py0 * 2;
  const int tid = threadIdx.x;
  const int lane = tid & 63, wid = tid >> 6;
  const int n = lane & 15, g = lane >> 4;

  const float* ib = in + (size_t)b * 109 * 109 * 8;
  float v[4][8];
#pragma unroll
  for (int u = 0; u < 4; ++u) {
    int pos = tid + u * 128;
    if (pos < 480) {
      int row = pos / 24, col = pos % 24;
      int gy = y0c + row;
      int gx = x0c + col; gx = gx < 108 ? gx : 108;
      const float* p = ib + ((size_t)gy * 109 + gx) * 8;
      float4 q0 = *(const float4*)p;
      float4 q1 = *(const float4*)(p + 4);
      v[u][0] = q0.x; v[u][1] = q0.y; v[u][2] = q0.z; v[u][3] = q0.w;
      v[u][4] = q1.x; v[u][5] = q1.y; v[u][6] = q1.z; v[u][7] = q1.w;
    }
  }
#pragma unroll
  for (int u = 0; u < 4; ++u) {
    int pos = tid + u * 128;
    if (pos < 480) {
      uint32_t hh[8], ll[8];
#pragma unroll
      for (int c = 0; c < 8; ++c) split1(v[u][c], hh[c], ll[c]);
      union { uint32_t w[4]; uint4 q; } H, L;
#pragma unroll
      for (int p2 = 0; p2 < 4; ++p2) {
        H.w[p2] = hh[2 * p2] | (hh[2 * p2 + 1] << 16);
        L.w[p2] = ll[2 * p2] | (ll[2 * p2 + 1] << 16);
      }
      *(uint4*)&sH[pos * 8] = H.q;
      *(uint4*)&sH[3840 + pos * 8] = L.q;
    }
  }
  __syncthreads();

  f32x4 acc[8];
#pragma unroll
  for (int i = 0; i < 8; ++i) acc[i] = (f32x4){0.f, 0.f, 0.f, 0.f};

  const int mg = n + 2 * g;
  const int rbase = wid * 8;
#pragma unroll
  for (int h = 0; h < 2; ++h) {
    BFrag bh[5], bl[5];
#pragma unroll
    for (int ky = 0; ky < 5; ++ky) {
      int idx = (((ky * 2 + h) * 4 + g) * 16 + n) * 8;
      uint4 th = *(const uint4*)&wpHi[idx];
      uint4 tl = *(const uint4*)&wpLo[idx];
      bh[ky].u[0] = th.x; bh[ky].u[1] = th.y;
      bh[ky].u[2] = th.z; bh[ky].u[3] = th.w;
      bl[ky].u[0] = tl.x; bl[ky].u[1] = tl.y;
      bl[ky].u[2] = tl.z; bl[ky].u[3] = tl.w;
    }
#pragma unroll
    for (int t = 0; t < 12; ++t) {
      const int s0 = ((rbase + t) * 24 + mg) * 8 + 4 * h;
      BFrag ah, al;
      ah.q[0] = *(const u64*)&sH[s0];
      ah.q[1] = *(const u64*)&sH[s0 + 8];
      al.q[0] = *(const u64*)&sH[3840 + s0];
      al.q[1] = *(const u64*)&sH[3840 + s0 + 8];
#pragma unroll
      for (int ky = 0; ky < 5; ++ky) {
        const int i = t - ky;
        if (i >= 0 && i < 8) {
          acc[i] = __builtin_amdgcn_mfma_f32_16x16x32_bf16(ah.v, bh[ky].v, acc[i], 0, 0, 0);
          acc[i] = __builtin_amdgcn_mfma_f32_16x16x32_bf16(ah.v, bl[ky].v, acc[i], 0, 0, 0);
          acc[i] = __builtin_amdgcn_mfma_f32_16x16x32_bf16(al.v, bh[ky].v, acc[i], 0, 0, 0);
        }
      }
    }
  }

  if (n < 10) {
    const float bs = bias[n];
    const int pxb = px0 + 2 * g;
    const int pyb = py0 + wid * 4;
#pragma unroll
    for (int u = 0; u < 4; ++u) {
      f32x4 A0 = acc[2 * u], A1 = acc[2 * u + 1];
      float m0 = fmaxf(fmaxf(A0[0], A0[1]), fmaxf(A1[0], A1[1])) + bs;
      float m1 = fmaxf(fmaxf(A0[2], A0[3]), fmaxf(A1[2], A1[3])) + bs;
      float* op = out + ((size_t)(b * 10 + n) * 52 + pyb + u) * 52 + pxb;
      op[0] = fmaxf(m0, 0.f);
      op[1] = fmaxf(m1, 0.f);
    }
  }
}

// ---------------------------------------------------------------------------
// K3: fc1 split-K partial GEMM, 256 blocks x 2 chunks of 64 (two-phase stage).
// ---------------------------------------------------------------------------
__global__ __launch_bounds__(256) void k3_fc1_partial(
    const float* __restrict__ xs, const float* __restrict__ w,
    float* __restrict__ part) {
  __shared__ float sA[128 * 64];
  __shared__ float sW[64 * 33];
  const int p = blockIdx.x;
  const int tid = threadIdx.x;
  const int n = tid & 31, bg = tid >> 5;
  float acc[16];
#pragma unroll
  for (int i = 0; i < 16; ++i) acc[i] = 0.f;

  for (int ch = 0; ch < 2; ++ch) {
    const int k0 = p * 128 + ch * 64;
    __syncthreads();
#pragma unroll
    for (int bb = 0; bb < 4; ++bb) {
      float v[8];
#pragma unroll
      for (int u = 0; u < 8; ++u) {
        int idx = bb * 2048 + u * 256 + tid;
        int bbv = idx >> 6, k = idx & 63;
        int gk = k0 + k;
        v[u] = (gk < 27040) ? xs[bbv * 27040 + gk] : 0.f;
      }
#pragma unroll
      for (int u = 0; u < 8; ++u) {
        int idx = bb * 2048 + u * 256 + tid;
        sA[idx] = v[u];
      }
    }
    {
      float v[8];
#pragma unroll
      for (int u = 0; u < 8; ++u) {
        int idx = u * 256 + tid;
        int nn = idx >> 6, k = idx & 63;
        int gk = k0 + k;
        v[u] = (gk < 27040) ? w[nn * 27040 + gk] : 0.f;
      }
#pragma unroll
      for (int u = 0; u < 8; ++u) {
        int idx = u * 256 + tid;
        int nn = idx >> 6, k = idx & 63;
        sW[k * 33 + nn] = v[u];
      }
    }
    __syncthreads();
    for (int k = 0; k < 64; k += 4) {
      float w0 = sW[(k + 0) * 33 + n];
      float w1 = sW[(k + 1) * 33 + n];
      float w2 = sW[(k + 2) * 33 + n];
      float w3 = sW[(k + 3) * 33 + n];
#pragma unroll
      for (int i = 0; i < 16; ++i) {
        float4 a = *(const float4*)&sA[(bg * 16 + i) * 64 + k];
        acc[i] = fmaf(a.x, w0, acc[i]);
        acc[i] = fmaf(a.y, w1, acc[i]);
        acc[i] = fmaf(a.z, w2, acc[i]);
        acc[i] = fmaf(a.w, w3, acc[i]);
      }
    }
  }
#pragma unroll
  for (int i = 0; i < 16; ++i)
    part[p * 4096 + (bg * 16 + i) * 32 + n] = acc[i];
}

// ---------------------------------------------------------------------------
// K4: reduce 256 partials -> h = relu(C + b1). 512 blocks, shfl-reduce.
// ---------------------------------------------------------------------------
__global__ __launch_bounds__(256) void k4_reduce(
    const float* __restrict__ part, const float* __restrict__ b1,
    float* __restrict__ h) {
  const int lane = threadIdx.x & 31;
  const int eloc = threadIdx.x >> 5;
  const int e = blockIdx.x * 8 + eloc;
  float s = 0.f;
#pragma unroll
  for (int pc = 0; pc < 8; ++pc) s += part[(pc * 32 + lane) * 4096 + e];
#pragma unroll
  for (int off = 16; off > 0; off >>= 1) s += __shfl_down(s, off, 32);
  if (lane == 0) h[e] = fmaxf(s + b1[e & 31], 0.f);
}

// ---------------------------------------------------------------------------
// K5: theta (recomputed per block) + fused affine_grid + bilinear sample.
// ---------------------------------------------------------------------------
__global__ __launch_bounds__(256) void k5_sample(
    const float* __restrict__ x, const float* __restrict__ h,
    const float* __restrict__ w2, const float* __restrict__ b2,
    float* __restrict__ out) {
  __shared__ float th[6];
  const int b = blockIdx.z;
  if (threadIdx.x < 6) {
    int j = threadIdx.x;
    float s = b2[j];
    for (int m = 0; m < 32; ++m) s = fmaf(h[b * 32 + m], w2[j * 32 + m], s);
    th[j] = s;
  }
  __syncthreads();

  const int pix = blockIdx.x * 256 + threadIdx.x;
  const int hh = pix / 224, ww = pix % 224;
  const float step = 2.0f / 223.0f;
  float gx = ww * step - 1.0f, gy = hh * step - 1.0f;
  float tx = th[0] * gx + th[1] * gy + th[2];
  float ty = th[3] * gx + th[4] * gy + th[5];
  float ix = (tx + 1.0f) * 0.5f * 223.0f;
  float iy = (ty + 1.0f) * 0.5f * 223.0f;
  float x0 = floorf(ix), y0 = floorf(iy);
  float x1 = x0 + 1.f, y1 = y0 + 1.f;
  float wx1 = ix - x0, wx0 = x1 - ix;
  float wy1 = iy - y0, wy0 = y1 - iy;
  float w00 = wx0 * wy0, w01 = wx1 * wy0, w10 = wx0 * wy1, w11 = wx1 * wy1;
  bool vx0 = (x0 >= 0.f) && (x0 <= 223.f);
  bool vx1 = (x1 >= 0.f) && (x1 <= 223.f);
  bool vy0 = (y0 >= 0.f) && (y0 <= 223.f);
  bool vy1 = (y1 >= 0.f) && (y1 <= 223.f);
  w00 = (vx0 && vy0) ? w00 : 0.f;
  w01 = (vx1 && vy0) ? w01 : 0.f;
  w10 = (vx0 && vy1) ? w10 : 0.f;
  w11 = (vx1 && vy1) ? w11 : 0.f;
  int xi0 = (int)fminf(fmaxf(x0, 0.f), 223.f);
  int xi1 = (int)fminf(fmaxf(x1, 0.f), 223.f);
  int yi0 = (int)fminf(fmaxf(y0, 0.f), 223.f);
  int yi1 = (int)fminf(fmaxf(y1, 0.f), 223.f);
#pragma unroll
  for (int c = 0; c < 3; ++c) {
    const float* img = x + (size_t)((b * 3 + c) * 224) * 224;
    float v = img[yi0 * 224 + xi0] * w00 + img[yi0 * 224 + xi1] * w01 +
              img[yi1 * 224 + xi0] * w10 + img[yi1 * 224 + xi1] * w11;
    out[((b * 3 + c) * 224 + hh) * 224 + ww] = v;
  }
}

extern "C" void kernel_launch(void* const* d_in, const int* in_sizes, int n_in,
                              void* d_out, int out_size, void* d_ws,
                              size_t ws_size, hipStream_t stream) {
  const float* x   = (const float*)d_in[0];
  const float* w1  = (const float*)d_in[1];
  const float* b1  = (const float*)d_in[2];
  const float* w2  = (const float*)d_in[3];
  const float* b2  = (const float*)d_in[4];
  const float* fw1 = (const float*)d_in[5];
  const float* fb1 = (const float*)d_in[6];
  const float* fw2 = (const float*)d_in[7];
  const float* fb2 = (const float*)d_in[8];
  float* out = (float*)d_out;

  float* ws   = (float*)d_ws;
  float* out1 = ws;                    // [128,109,109,8] ch-last = 12,166,144
  float* xs   = out1 + 12166144;       // [128,10,52,52]  =  3,461,120 f32
  float* part = xs + 3461120;          // [256,128,32]    =  1,048,576 f32
  float* hbuf = part + 1048576;        // [128,32]        =      4,096 f32
  unsigned short* wpHi  = (unsigned short*)(hbuf + 4096);  // 4096 us
  unsigned short* wpLo  = wpHi + 4096;                     // 4096 us
  unsigned short* wp2Hi = wpLo + 4096;                     // 5120 us
  unsigned short* wp2Lo = wp2Hi + 5120;                    // 5120 us

  k0_wprep<<<20, 256, 0, stream>>>(w1, w2, wpHi, wpLo, wp2Hi, wp2Lo);
  k1_mfma<<<dim3(7, 4, 128), 512, 0, stream>>>(x, wpHi, wpLo, b1, out1);
  k2_mfma<<<dim3(7, 7, 128), 128, 0, stream>>>(out1, wp2Hi, wp2Lo, b2, xs);
  k3_fc1_partial<<<256, 256, 0, stream>>>(xs, fw1, part);
  k4_reduce<<<512, 256, 0, stream>>>(part, fb1, hbuf);
  k5_sample<<<dim3(196, 1, 128), 256, 0, stream>>>(x, hbuf, fw2, fb2, out);
}

// Round 16
// 186.153 us; speedup vs baseline: 1.4734x; 1.0754x over previous
//
#include <hip/hip_runtime.h>
#include <hip/hip_bf16.h>
#include <stdint.h>

typedef __bf16 bf16x8 __attribute__((ext_vector_type(8)));
typedef float f32x4 __attribute__((ext_vector_type(4)));
typedef unsigned long long u64;

union BFrag { uint32_t u[4]; u64 q[2]; bf16x8 v; };
union R16 { uint4 v; u64 q[2]; };

// truncation split: f = hi + lo (err ~2^-17 after 3-term MFMA)
__device__ __forceinline__ void split1(float f, uint32_t& hi, uint32_t& lo) {
  uint32_t b = __float_as_uint(f);
  hi = b >> 16;
  float fl = f - __uint_as_float(b & 0xFFFF0000u);
  lo = __float_as_uint(fl) >> 16;
}

// ---------------------------------------------------------------------------
// K0 (merged): pack conv1 AND conv2 weights into MFMA B-fragment tables.
// ---------------------------------------------------------------------------
__global__ __launch_bounds__(256) void k0_wprep(
    const float* __restrict__ w1, const float* __restrict__ w2,
    unsigned short* __restrict__ wpHi, unsigned short* __restrict__ wpLo,
    unsigned short* __restrict__ wp2Hi, unsigned short* __restrict__ wp2Lo) {
  int id = blockIdx.x * 256 + threadIdx.x;
  if (id < 4096) {
    int j = id & 7, n = (id >> 3) & 15, g = (id >> 7) & 3, jf = id >> 9;
    int o = n & 7, half = n >> 3;
    int ky = jf - half, c = j & 3, kx = 2 * g + (j >> 2);
    float f = 0.f;
    if (c < 3 && kx < 7 && ky >= 0 && ky < 7)
      f = w1[o * 147 + c * 49 + ky * 7 + kx];
    uint32_t h, l;
    split1(f, h, l);
    wpHi[id] = (unsigned short)h;
    wpLo[id] = (unsigned short)l;
  }
  if (id < 5120) {
    int j = id & 7, n = (id >> 3) & 15, g = (id >> 7) & 3;
    int hk = id >> 9;
    int h = hk & 1, ky = hk >> 1;
    int c = 4 * h + (j & 3), kx = 2 * g + (j >> 2);
    float f = 0.f;
    if (n < 10 && kx < 5)
      f = w2[n * 200 + c * 25 + ky * 5 + kx];
    uint32_t hh, ll;
    split1(f, hh, ll);
    wp2Hi[id] = (unsigned short)hh;
    wp2Lo[id] = (unsigned short)ll;
  }
}

// ---------------------------------------------------------------------------
// K1 v6: conv1 + maxpool2 + relu, MFMA 16x16x32 bf16, 3-term hi/lo.
// LDS interleaved [row][col][4 hi | 4 lo] -> 2 ds_read_b128 per t.
// Term-major MFMA sweeps (dep distance 8). 32-wide x-tile, 512 thr.
// ---------------------------------------------------------------------------
__global__ __launch_bounds__(512) void k1_mfma(
    const float* __restrict__ x, const unsigned short* __restrict__ wpHi,
    const unsigned short* __restrict__ wpLo, const float* __restrict__ bias,
    float* __restrict__ out) {
  __shared__ unsigned short sI[70 * 40 * 8];  // 44.8 KB
  const int b = blockIdx.z;
  const int x0 = blockIdx.x * 32;
  const int y0blk = blockIdx.y * 64;
  const int tid = threadIdx.x;
  const int lane = tid & 63, wid = tid >> 6;
  const int n = lane & 15, g = lane >> 4;
  const int xh = wid & 1, yq = wid >> 1;

  BFrag bhi[8], blo[8];
#pragma unroll
  for (int jf = 0; jf < 8; ++jf) {
    uint4 th = *(const uint4*)&wpHi[((jf * 4 + g) * 16 + n) * 8];
    uint4 tl = *(const uint4*)&wpLo[((jf * 4 + g) * 16 + n) * 8];
    bhi[jf].u[0] = th.x; bhi[jf].u[1] = th.y;
    bhi[jf].u[2] = th.z; bhi[jf].u[3] = th.w;
    blo[jf].u[0] = tl.x; blo[jf].u[1] = tl.y;
    blo[jf].u[2] = tl.z; blo[jf].u[3] = tl.w;
  }

  // ---- two-phase staging: 70 rows x 40 cols x 3 ch, hi/lo interleaved
  const float* xb = x + (size_t)b * 3 * 50176;
  float pv0[6], pv1[6], pv2[6];
#pragma unroll
  for (int u = 0; u < 6; ++u) {
    int pos = tid + u * 512;
    if (pos < 2800) {
      int row = pos / 40, col = pos % 40;
      int gy = y0blk + row; gy = gy < 223 ? gy : 223;
      int gx = x0 + col;    gx = gx < 223 ? gx : 223;
      const float* p = xb + (size_t)gy * 224 + gx;
      pv0[u] = p[0];
      pv1[u] = p[50176];
      pv2[u] = p[100352];
    }
  }
#pragma unroll
  for (int u = 0; u < 6; ++u) {
    int pos = tid + u * 512;
    if (pos < 2800) {
      uint32_t h0, l0, h1, l1, h2, l2;
      split1(pv0[u], h0, l0);
      split1(pv1[u], h1, l1);
      split1(pv2[u], h2, l2);
      uint4 q;
      q.x = h0 | (h1 << 16);
      q.y = h2;
      q.z = l0 | (l1 << 16);
      q.w = l2;
      *(uint4*)&sI[pos * 8] = q;
    }
  }
  __syncthreads();

  const int y0w = y0blk + yq * 16;
  if (y0w <= 217) {
    f32x4 acc[8];
#pragma unroll
    for (int i = 0; i < 8; ++i) acc[i] = (f32x4){0.f, 0.f, 0.f, 0.f};

    const int mg = xh * 16 + n + 2 * g;
    const int rbase = yq * 16;
#pragma unroll
    for (int t = 0; t < 22; ++t) {
      const int s0 = ((rbase + t) * 40 + mg) * 8;
      R16 r0, r1;
      r0.v = *(const uint4*)&sI[s0];
      r1.v = *(const uint4*)&sI[s0 + 8];
      BFrag ah, al;
      ah.q[0] = r0.q[0]; al.q[0] = r0.q[1];
      ah.q[1] = r1.q[0]; al.q[1] = r1.q[1];
      // term-major sweeps: consecutive MFMAs hit different accumulators
#pragma unroll
      for (int i = 0; i < 8; ++i) {
        const int jf = t - 2 * i;
        if (jf >= 0 && jf < 8)
          acc[i] = __builtin_amdgcn_mfma_f32_16x16x32_bf16(ah.v, bhi[jf].v, acc[i], 0, 0, 0);
      }
#pragma unroll
      for (int i = 0; i < 8; ++i) {
        const int jf = t - 2 * i;
        if (jf >= 0 && jf < 8)
          acc[i] = __builtin_amdgcn_mfma_f32_16x16x32_bf16(ah.v, blo[jf].v, acc[i], 0, 0, 0);
      }
#pragma unroll
      for (int i = 0; i < 8; ++i) {
        const int jf = t - 2 * i;
        if (jf >= 0 && jf < 8)
          acc[i] = __builtin_amdgcn_mfma_f32_16x16x32_bf16(al.v, bhi[jf].v, acc[i], 0, 0, 0);
      }
    }

    // ---- epilogue: pool-x in-lane, pool-y via shfl_xor(8); channels-last
    const int o = n & 7;
    const float bs = bias[o];
    const int px0 = x0 / 2 + xh * 8 + 2 * g;
    const int py0 = y0w / 2;
#pragma unroll
    for (int i = 0; i < 8; ++i) {
      float v0 = fmaxf(acc[i][0], acc[i][1]);
      float v1 = fmaxf(acc[i][2], acc[i][3]);
      float p0 = __shfl_xor(v0, 8, 64);
      float p1 = __shfl_xor(v1, 8, 64);
      const int py = py0 + i;
      if (n < 8 && py < 109) {
        float m0 = fmaxf(v0, p0) + bs;
        float m1 = fmaxf(v1, p1) + bs;
        float* op = out + (((size_t)(b * 109 + py)) * 109 + px0) * 8 + o;
        if (px0 < 109)     op[0] = fmaxf(m0, 0.f);
        if (px0 + 1 < 109) op[8] = fmaxf(m1, 0.f);
      }
    }
  }
}

// ---------------------------------------------------------------------------
// K2 v4: conv2 + maxpool2 + relu via MFMA, 3-term hi/lo.
// LDS interleaved [row][col][half h][4 hi | 4 lo] -> 2 ds_read_b128 per (h,t).
// Term-major MFMA sweeps. Channels-last input.
// ---------------------------------------------------------------------------
__global__ __launch_bounds__(128) void k2_mfma(
    const float* __restrict__ in, const unsigned short* __restrict__ wpHi,
    const unsigned short* __restrict__ wpLo, const float* __restrict__ bias,
    float* __restrict__ out) {
  __shared__ unsigned short sI[20 * 24 * 16];  // 15.4 KB
  const int b = blockIdx.z;
  const int px0 = (blockIdx.x < 6) ? blockIdx.x * 8 : 44;
  const int py0 = (blockIdx.y < 6) ? blockIdx.y * 8 : 44;
  const int x0c = px0 * 2, y0c = py0 * 2;
  const int tid = threadIdx.x;
  const int lane = tid & 63, wid = tid >> 6;
  const int n = lane & 15, g = lane >> 4;

  const float* ib = in + (size_t)b * 109 * 109 * 8;
  float v[4][8];
#pragma unroll
  for (int u = 0; u < 4; ++u) {
    int pos = tid + u * 128;
    if (pos < 480) {
      int row = pos / 24, col = pos % 24;
      int gy = y0c + row;
      int gx = x0c + col; gx = gx < 108 ? gx : 108;
      const float* p = ib + ((size_t)gy * 109 + gx) * 8;
      float4 q0 = *(const float4*)p;
      float4 q1 = *(const float4*)(p + 4);
      v[u][0] = q0.x; v[u][1] = q0.y; v[u][2] = q0.z; v[u][3] = q0.w;
      v[u][4] = q1.x; v[u][5] = q1.y; v[u][6] = q1.z; v[u][7] = q1.w;
    }
  }
#pragma unroll
  for (int u = 0; u < 4; ++u) {
    int pos = tid + u * 128;
    if (pos < 480) {
      uint32_t hh[8], ll[8];
#pragma unroll
      for (int c = 0; c < 8; ++c) split1(v[u][c], hh[c], ll[c]);
      uint4 q0, q1;
      q0.x = hh[0] | (hh[1] << 16); q0.y = hh[2] | (hh[3] << 16);
      q0.z = ll[0] | (ll[1] << 16); q0.w = ll[2] | (ll[3] << 16);
      q1.x = hh[4] | (hh[5] << 16); q1.y = hh[6] | (hh[7] << 16);
      q1.z = ll[4] | (ll[5] << 16); q1.w = ll[6] | (ll[7] << 16);
      *(uint4*)&sI[pos * 16] = q0;
      *(uint4*)&sI[pos * 16 + 8] = q1;
    }
  }
  __syncthreads();

  f32x4 acc[8];
#pragma unroll
  for (int i = 0; i < 8; ++i) acc[i] = (f32x4){0.f, 0.f, 0.f, 0.f};

  const int mg = n + 2 * g;
  const int rbase = wid * 8;
#pragma unroll
  for (int h = 0; h < 2; ++h) {
    BFrag bh[5], bl[5];
#pragma unroll
    for (int ky = 0; ky < 5; ++ky) {
      int idx = (((ky * 2 + h) * 4 + g) * 16 + n) * 8;
      uint4 th = *(const uint4*)&wpHi[idx];
      uint4 tl = *(const uint4*)&wpLo[idx];
      bh[ky].u[0] = th.x; bh[ky].u[1] = th.y;
      bh[ky].u[2] = th.z; bh[ky].u[3] = th.w;
      bl[ky].u[0] = tl.x; bl[ky].u[1] = tl.y;
      bl[ky].u[2] = tl.z; bl[ky].u[3] = tl.w;
    }
#pragma unroll
    for (int t = 0; t < 12; ++t) {
      const int s0 = ((rbase + t) * 24 + mg) * 16 + h * 8;
      R16 r0, r1;
      r0.v = *(const uint4*)&sI[s0];
      r1.v = *(const uint4*)&sI[s0 + 16];
      BFrag ah, al;
      ah.q[0] = r0.q[0]; al.q[0] = r0.q[1];
      ah.q[1] = r1.q[0]; al.q[1] = r1.q[1];
#pragma unroll
      for (int ky = 0; ky < 5; ++ky) {
        const int i = t - ky;
        if (i >= 0 && i < 8)
          acc[i] = __builtin_amdgcn_mfma_f32_16x16x32_bf16(ah.v, bh[ky].v, acc[i], 0, 0, 0);
      }
#pragma unroll
      for (int ky = 0; ky < 5; ++ky) {
        const int i = t - ky;
        if (i >= 0 && i < 8)
          acc[i] = __builtin_amdgcn_mfma_f32_16x16x32_bf16(ah.v, bl[ky].v, acc[i], 0, 0, 0);
      }
#pragma unroll
      for (int ky = 0; ky < 5; ++ky) {
        const int i = t - ky;
        if (i >= 0 && i < 8)
          acc[i] = __builtin_amdgcn_mfma_f32_16x16x32_bf16(al.v, bh[ky].v, acc[i], 0, 0, 0);
      }
    }
  }

  if (n < 10) {
    const float bs = bias[n];
    const int pxb = px0 + 2 * g;
    const int pyb = py0 + wid * 4;
#pragma unroll
    for (int u = 0; u < 4; ++u) {
      f32x4 A0 = acc[2 * u], A1 = acc[2 * u + 1];
      float m0 = fmaxf(fmaxf(A0[0], A0[1]), fmaxf(A1[0], A1[1])) + bs;
      float m1 = fmaxf(fmaxf(A0[2], A0[3]), fmaxf(A1[2], A1[3])) + bs;
      float* op = out + ((size_t)(b * 10 + n) * 52 + pyb + u) * 52 + pxb;
      op[0] = fmaxf(m0, 0.f);
      op[1] = fmaxf(m1, 0.f);
    }
  }
}

// ---------------------------------------------------------------------------
// K3: fc1 split-K partial GEMM, 256 blocks x 2 chunks of 64 (two-phase stage).
// ---------------------------------------------------------------------------
__global__ __launch_bounds__(256) void k3_fc1_partial(
    const float* __restrict__ xs, const float* __restrict__ w,
    float* __restrict__ part) {
  __shared__ float sA[128 * 64];
  __shared__ float sW[64 * 33];
  const int p = blockIdx.x;
  const int tid = threadIdx.x;
  const int n = tid & 31, bg = tid >> 5;
  float acc[16];
#pragma unroll
  for (int i = 0; i < 16; ++i) acc[i] = 0.f;

  for (int ch = 0; ch < 2; ++ch) {
    const int k0 = p * 128 + ch * 64;
    __syncthreads();
#pragma unroll
    for (int bb = 0; bb < 4; ++bb) {
      float v[8];
#pragma unroll
      for (int u = 0; u < 8; ++u) {
        int idx = bb * 2048 + u * 256 + tid;
        int bbv = idx >> 6, k = idx & 63;
        int gk = k0 + k;
        v[u] = (gk < 27040) ? xs[bbv * 27040 + gk] : 0.f;
      }
#pragma unroll
      for (int u = 0; u < 8; ++u) {
        int idx = bb * 2048 + u * 256 + tid;
        sA[idx] = v[u];
      }
    }
    {
      float v[8];
#pragma unroll
      for (int u = 0; u < 8; ++u) {
        int idx = u * 256 + tid;
        int nn = idx >> 6, k = idx & 63;
        int gk = k0 + k;
        v[u] = (gk < 27040) ? w[nn * 27040 + gk] : 0.f;
      }
#pragma unroll
      for (int u = 0; u < 8; ++u) {
        int idx = u * 256 + tid;
        int nn = idx >> 6, k = idx & 63;
        sW[k * 33 + nn] = v[u];
      }
    }
    __syncthreads();
    for (int k = 0; k < 64; k += 4) {
      float w0 = sW[(k + 0) * 33 + n];
      float w1 = sW[(k + 1) * 33 + n];
      float w2 = sW[(k + 2) * 33 + n];
      float w3 = sW[(k + 3) * 33 + n];
#pragma unroll
      for (int i = 0; i < 16; ++i) {
        float4 a = *(const float4*)&sA[(bg * 16 + i) * 64 + k];
        acc[i] = fmaf(a.x, w0, acc[i]);
        acc[i] = fmaf(a.y, w1, acc[i]);
        acc[i] = fmaf(a.z, w2, acc[i]);
        acc[i] = fmaf(a.w, w3, acc[i]);
      }
    }
  }
#pragma unroll
  for (int i = 0; i < 16; ++i)
    part[p * 4096 + (bg * 16 + i) * 32 + n] = acc[i];
}

// ---------------------------------------------------------------------------
// K4: reduce 256 partials -> h = relu(C + b1). 512 blocks, shfl-reduce.
// ---------------------------------------------------------------------------
__global__ __launch_bounds__(256) void k4_reduce(
    const float* __restrict__ part, const float* __restrict__ b1,
    float* __restrict__ h) {
  const int lane = threadIdx.x & 31;
  const int eloc = threadIdx.x >> 5;
  const int e = blockIdx.x * 8 + eloc;
  float s = 0.f;
#pragma unroll
  for (int pc = 0; pc < 8; ++pc) s += part[(pc * 32 + lane) * 4096 + e];
#pragma unroll
  for (int off = 16; off > 0; off >>= 1) s += __shfl_down(s, off, 32);
  if (lane == 0) h[e] = fmaxf(s + b1[e & 31], 0.f);
}

// ---------------------------------------------------------------------------
// K5: theta (recomputed per block) + fused affine_grid + bilinear sample.
// ---------------------------------------------------------------------------
__global__ __launch_bounds__(256) void k5_sample(
    const float* __restrict__ x, const float* __restrict__ h,
    const float* __restrict__ w2, const float* __restrict__ b2,
    float* __restrict__ out) {
  __shared__ float th[6];
  const int b = blockIdx.z;
  if (threadIdx.x < 6) {
    int j = threadIdx.x;
    float s = b2[j];
    for (int m = 0; m < 32; ++m) s = fmaf(h[b * 32 + m], w2[j * 32 + m], s);
    th[j] = s;
  }
  __syncthreads();

  const int pix = blockIdx.x * 256 + threadIdx.x;
  const int hh = pix / 224, ww = pix % 224;
  const float step = 2.0f / 223.0f;
  float gx = ww * step - 1.0f, gy = hh * step - 1.0f;
  float tx = th[0] * gx + th[1] * gy + th[2];
  float ty = th[3] * gx + th[4] * gy + th[5];
  float ix = (tx + 1.0f) * 0.5f * 223.0f;
  float iy = (ty + 1.0f) * 0.5f * 223.0f;
  float x0 = floorf(ix), y0 = floorf(iy);
  float x1 = x0 + 1.f, y1 = y0 + 1.f;
  float wx1 = ix - x0, wx0 = x1 - ix;
  float wy1 = iy - y0, wy0 = y1 - iy;
  float w00 = wx0 * wy0, w01 = wx1 * wy0, w10 = wx0 * wy1, w11 = wx1 * wy1;
  bool vx0 = (x0 >= 0.f) && (x0 <= 223.f);
  bool vx1 = (x1 >= 0.f) && (x1 <= 223.f);
  bool vy0 = (y0 >= 0.f) && (y0 <= 223.f);
  bool vy1 = (y1 >= 0.f) && (y1 <= 223.f);
  w00 = (vx0 && vy0) ? w00 : 0.f;
  w01 = (vx1 && vy0) ? w01 : 0.f;
  w10 = (vx0 && vy1) ? w10 : 0.f;
  w11 = (vx1 && vy1) ? w11 : 0.f;
  int xi0 = (int)fminf(fmaxf(x0, 0.f), 223.f);
  int xi1 = (int)fminf(fmaxf(x1, 0.f), 223.f);
  int yi0 = (int)fminf(fmaxf(y0, 0.f), 223.f);
  int yi1 = (int)fminf(fmaxf(y1, 0.f), 223.f);
#pragma unroll
  for (int c = 0; c < 3; ++c) {
    const float* img = x + (size_t)((b * 3 + c) * 224) * 224;
    float v = img[yi0 * 224 + xi0] * w00 + img[yi0 * 224 + xi1] * w01 +
              img[yi1 * 224 + xi0] * w10 + img[yi1 * 224 + xi1] * w11;
    out[((b * 3 + c) * 224 + hh) * 224 + ww] = v;
  }
}

extern "C" void kernel_launch(void* const* d_in, const int* in_sizes, int n_in,
                              void* d_out, int out_size, void* d_ws,
                              size_t ws_size, hipStream_t stream) {
  const float* x   = (const float*)d_in[0];
  const float* w1  = (const float*)d_in[1];
  const float* b1  = (const float*)d_in[2];
  const float* w2  = (const float*)d_in[3];
  const float* b2  = (const float*)d_in[4];
  const float* fw1 = (const float*)d_in[5];
  const float* fb1 = (const float*)d_in[6];
  const float* fw2 = (const float*)d_in[7];
  const float* fb2 = (const float*)d_in[8];
  float* out = (float*)d_out;

  float* ws   = (float*)d_ws;
  float* out1 = ws;                    // [128,109,109,8] ch-last = 12,166,144
  float* xs   = out1 + 12166144;       // [128,10,52,52]  =  3,461,120 f32
  float* part = xs + 3461120;          // [256,128,32]    =  1,048,576 f32
  float* hbuf = part + 1048576;        // [128,32]        =      4,096 f32
  unsigned short* wpHi  = (unsigned short*)(hbuf + 4096);  // 4096 us
  unsigned short* wpLo  = wpHi + 4096;                     // 4096 us
  unsigned short* wp2Hi = wpLo + 4096;                     // 5120 us
  unsigned short* wp2Lo = wp2Hi + 5120;                    // 5120 us

  k0_wprep<<<20, 256, 0, stream>>>(w1, w2, wpHi, wpLo, wp2Hi, wp2Lo);
  k1_mfma<<<dim3(7, 4, 128), 512, 0, stream>>>(x, wpHi, wpLo, b1, out1);
  k2_mfma<<<dim3(7, 7, 128), 128, 0, stream>>>(out1, wp2Hi, wp2Lo, b2, xs);
  k3_fc1_partial<<<256, 256, 0, stream>>>(xs, fw1, part);
  k4_reduce<<<512, 256, 0, stream>>>(part, fb1, hbuf);
  k5_sample<<<dim3(196, 1, 128), 256, 0, stream>>>(x, hbuf, fw2, fb2, out);
}